// Round 7
// baseline (548.288 us; speedup 1.0000x reference)
//
#include <hip/hip_runtime.h>
#include <math.h>

#define HW 4096   // 64*64

typedef __attribute__((ext_vector_type(8))) short short8;
typedef __attribute__((ext_vector_type(4))) float floatx4;
typedef __attribute__((ext_vector_type(2))) float floatx2;

__device__ inline unsigned short f2bf(float f) {
    unsigned int u = __float_as_uint(f);
    unsigned int r = (u + 0x7fffu + ((u >> 16) & 1u)) >> 16;
    return (unsigned short)r;
}
__device__ inline float bf2f(unsigned short u) {
    return __uint_as_float(((unsigned int)u) << 16);
}

// Fragment-pack index helpers.
// A-frag pack of matrix M[R rows][K cols]: element (r,k) at
//   tile(r>>4, k>>5)*512 + ((k>>3)&3)*128 + (r&15)*8 + (k&7); wave loads base + tile*512 + lane*8.
// xt (conv activations) layout: [b][ci>>3][row(68)][col(68)][ci&7].

// ---------------- fused setup: zero padded xt + 4 weight prepacks
__device__ inline void prepack_dev(const float* __restrict__ w, unsigned short* __restrict__ wp,
                                   int CO, int CI, int KK, int i)
{
    if (i >= CO * CI * KK) return;
    int ci = i % CI;
    int t = i / CI;
    int co = t % CO;
    int kk = t / CO;
    int ti = (kk * (CO >> 4) + (co >> 4)) * (CI >> 5) + (ci >> 5);
    wp[(size_t)ti * 512 + ((ci >> 3) & 3) * 128 + (co & 15) * 8 + (ci & 7)]
        = f2bf(w[(co * CI + ci) * KK + kk]);
}

__global__ void setup_kernel(uint4* __restrict__ zp, int zn,
                             const float* __restrict__ w0, unsigned short* __restrict__ wp0,
                             const float* __restrict__ w1, unsigned short* __restrict__ wp1,
                             const float* __restrict__ w2, unsigned short* __restrict__ wp2,
                             const float* __restrict__ w3, unsigned short* __restrict__ wp3)
{
    int bx = blockIdx.x, tid = threadIdx.x;
    if (bx < 2312) {
        int i = bx * 256 + tid;
        if (i < zn) zp[i] = make_uint4(0u, 0u, 0u, 0u);
    } else if (bx < 2600) {
        prepack_dev(w0, wp0, 64, 128, 9,  (bx - 2312) * 256 + tid);
    } else if (bx < 3400) {
        prepack_dev(w1, wp1, 64, 128, 25, (bx - 2600) * 256 + tid);
    } else if (bx < 3976) {
        prepack_dev(w2, wp2, 128, 128, 9, (bx - 3400) * 256 + tid);
    } else {
        prepack_dev(w3, wp3, 128, 128, 25,(bx - 3976) * 256 + tid);
    }
}

// ---------------- 1x1 conv: 2 px/thread (float2), 8 co/thread, weights in LDS
__global__ void __launch_bounds__(256)
conv1x1_v2(const float* __restrict__ in, const float* __restrict__ w,
           const float* __restrict__ bias, float* __restrict__ out,
           int CI, int CO, int do_affine,
           const float* __restrict__ s, const float* __restrict__ o,
           const float* __restrict__ addbuf, unsigned short* __restrict__ xt)
{
    __shared__ float wl[2048];
    int tid = threadIdx.x;
    int c0 = blockIdx.y * 8;
    int b = blockIdx.z;
    for (int i = tid; i < CI * 8; i += 256) {
        int k = i & 7, ci = i >> 3;
        wl[i] = w[(c0 + k) * CI + ci];
    }
    __syncthreads();
    int m = blockIdx.x * 512 + tid * 2;
    floatx2 acc[8];
#pragma unroll
    for (int k = 0; k < 8; ++k) {
        float bv = bias[c0 + k];
        acc[k] = (floatx2){bv, bv};
    }
    const float* inb = in + (size_t)b * CI * HW + m;
#pragma unroll 4
    for (int ci = 0; ci < CI; ++ci) {
        floatx2 v = *(const floatx2*)(inb + (size_t)ci * HW);
#pragma unroll
        for (int k = 0; k < 8; ++k) acc[k] += wl[ci * 8 + k] * v;
    }
#pragma unroll
    for (int k = 0; k < 8; ++k) {
        floatx2 v = acc[k];
        if (do_affine) {
            float sc = s[c0 + k], of = o[c0 + k];
            v[0] = fmaxf(v[0], 0.f) * sc + of;
            v[1] = fmaxf(v[1], 0.f) * sc + of;
        }
        size_t oidx = ((size_t)(b * CO + c0 + k)) * HW + m;
        if (addbuf) v += *(const floatx2*)(addbuf + oidx);
        *(floatx2*)(out + oidx) = v;
        acc[k] = v;
    }
    if (xt) {
#pragma unroll
        for (int r = 0; r < 2; ++r) {
            int mm = m + r;
            union { unsigned short u16[8]; uint4 q; } pk;
#pragma unroll
            for (int k = 0; k < 8; ++k) pk.u16[k] = f2bf(acc[k][r]);
            int h = mm >> 6, wc = mm & 63;
            // chunked layout [b][c0>>3][row][col][8]
            *(uint4*)(xt + ((size_t)(b * 16 + (c0 >> 3)) * 4624 + (h + 2) * 68 + (wc + 2)) * 8) = pk.q;
        }
    }
}

// ---------------- KxK conv as implicit-GEMM bf16 MFMA, m-split MS for occupancy
template<int K, int CO, int NB, int MS>
__global__ void __launch_bounds__(256)
convk_mfma(const unsigned short* __restrict__ xt, const unsigned short* __restrict__ wp,
           const float* __restrict__ bias, float* __restrict__ out,
           int OB, int co_off, int do_affine,
           const float* __restrict__ s, const float* __restrict__ o,
           unsigned short* __restrict__ incT)
{
    constexpr int CI = 128;
    constexpr int PAD = K / 2;
    constexpr int RO = 2 - PAD;
    constexpr int MT = 4 / MS;
    constexpr int CO16 = CO >> 4;
    constexpr int CI32 = CI >> 5;
    int tid = threadIdx.x;
    int wave = tid >> 6, lane = tid & 63;
    int h = blockIdx.x / MS, msb = blockIdx.x % MS;
    int b = blockIdx.y;
    int co0 = wave * 16 * NB;
    int n = lane & 15, q = lane >> 4;
    floatx4 acc[MT][NB];
#pragma unroll
    for (int mt = 0; mt < MT; ++mt)
#pragma unroll
        for (int nt = 0; nt < NB; ++nt) acc[mt][nt] = (floatx4){0.f, 0.f, 0.f, 0.f};

    const unsigned short* xb = xt + (size_t)(b * 16) * 4624 * 8;
    int mbase = msb * MT * 16;
    for (int ci0 = 0; ci0 < CI; ci0 += 32) {
#pragma unroll
        for (int kh = 0; kh < K; ++kh) {
            const unsigned short* xrow = xb + (size_t)(((ci0 >> 3) + q) * 4624 + (h + kh + RO) * 68 + RO) * 8;
            const unsigned short* wkh = wp + ((size_t)(kh * K) * CO16 * CI32 + (ci0 >> 5)) * 512 + lane * 8;
#pragma unroll
            for (int kw = 0; kw < K; ++kw) {
                short8 bfr[NB];
#pragma unroll
                for (int nt = 0; nt < NB; ++nt)
                    bfr[nt] = *(const short8*)(wkh + (size_t)((kw * CO16 + (co0 >> 4) + nt) * CI32) * 512);
#pragma unroll
                for (int mt = 0; mt < MT; ++mt) {
                    short8 afr = *(const short8*)(xrow + (mbase + mt * 16 + n + kw) * 8);
#pragma unroll
                    for (int nt = 0; nt < NB; ++nt)
                        acc[mt][nt] = __builtin_amdgcn_mfma_f32_16x16x32_bf16(afr, bfr[nt], acc[mt][nt], 0, 0, 0);
                }
            }
        }
    }
    int px0 = h * 64 + mbase + q * 4;
#pragma unroll
    for (int nt = 0; nt < NB; ++nt) {
        int co = co0 + nt * 16 + n;
        float bi = bias[co];
        float sc = do_affine ? s[co] : 1.f;
        float of = do_affine ? o[co] : 0.f;
        float* ob = out + ((size_t)(b * OB + co_off + co)) * HW;
        unsigned short* tb = incT ? incT + (size_t)b * 524288 : nullptr;
        int cpart = (co >> 5) * 512 + ((co >> 3) & 3) * 128 + (co & 7);
#pragma unroll
        for (int mt = 0; mt < MT; ++mt)
#pragma unroll
            for (int r = 0; r < 4; ++r) {
                int px = px0 + mt * 16 + r;
                float v = acc[mt][nt][r] + bi;
                if (do_affine) v = fmaxf(v, 0.f) * sc + of;
                ob[px] = v;
                if (incT) tb[(size_t)((px >> 4) * 2048 + cpart + (px & 15) * 8)] = f2bf(v);
            }
    }
}

// ---------------- cosine similarity over groups of 128 consecutive floats
__global__ void sim_kernel(const float* __restrict__ r1, const float* __restrict__ r2,
                           float* __restrict__ sim)
{
    int gw = blockIdx.x * 4 + (threadIdx.x >> 6);
    int lane = threadIdx.x & 63;
    int b = gw >> 12, n = gw & 4095;
    const float* p1 = r1 + (size_t)b * 524288 + (size_t)n * 128;
    const float* p2 = r2 + (size_t)b * 524288 + (size_t)n * 128;
    float a0 = p1[lane], a1 = p1[lane + 64];
    float b0 = p2[lane], b1 = p2[lane + 64];
    float dot = a0 * b0 + a1 * b1;
    float n1 = a0 * a0 + a1 * a1;
    float n2 = b0 * b0 + b1 * b1;
    for (int m = 32; m; m >>= 1) {
        dot += __shfl_xor(dot, m);
        n1  += __shfl_xor(n1, m);
        n2  += __shfl_xor(n2, m);
    }
    if (lane == 0) sim[b * 4096 + n] = dot / fmaxf(sqrtf(n1) * sqrtf(n2), 1e-8f);
}

// ---------------- x = concat(dif1, dif2): LDS-transposed, coalesced
__global__ void __launch_bounds__(256)
x_kernel2(const float* __restrict__ r1, const float* __restrict__ r2,
          const float* __restrict__ sim, float* __restrict__ xo)
{
    __shared__ float ls1[32 * 129], ls2[32 * 129];
    int b = blockIdx.y, p0 = blockIdx.x * 32, tid = threadIdx.x;
    const float* F1 = r1 + (size_t)b * 524288;
    const float* F2 = r2 + (size_t)b * 524288;
    for (int i = tid; i < 32 * 128; i += 256) {
        int p = i >> 7, c = i & 127;
        ls1[p * 129 + c] = F1[p0 * 128 + i];
        ls2[p * 129 + c] = F2[p0 * 128 + i];
    }
    __syncthreads();
    for (int j = tid; j < 256 * 32; j += 256) {
        int p = j & 31, cc = j >> 5;
        int c = cc & 127;
        float sv = sim[b * 4096 + p0 + p];
        const float* F = (cc & 128) ? F2 : F1;
        float t1v = ((cc & 128) ? ls2 : ls1)[p * 129 + c];
        xo[(size_t)b * 1048576 + (size_t)cc * 4096 + p0 + p] = t1v * (1.f - sv) + F[(size_t)c * 4096 + p0 + p];
    }
}

// ---------------- attn = avgpool2(|sim1-sim2|) -> A-frag-packed bf16, channel-split
__global__ void __launch_bounds__(256)
simp_kernel3(const float* __restrict__ r1, const float* __restrict__ r2,
             const float* __restrict__ sim, unsigned short* __restrict__ attn_pk)
{
    __shared__ float lsd[64 * 33];
    int b = blockIdx.y, h2 = blockIdx.x, cg = blockIdx.z, tid = threadIdx.x;
    const float* F1 = r1 + (size_t)b * 524288;
    const float* F2 = r2 + (size_t)b * 524288;
    const float* sb = sim + b * 4096;
    int w2 = tid & 31, cl = tid >> 5;
    float acc[4] = {};
    for (int dh = 0; dh < 2; ++dh) {
        int prow = h2 * 128 + dh * 64;
        __syncthreads();
        for (int i = tid; i < 64 * 32; i += 256) {
            int p = i >> 5, c = i & 31;
            size_t gi = (size_t)(prow + p) * 128 + cg * 32 + c;
            lsd[p * 33 + c] = F1[gi] - F2[gi];
        }
        __syncthreads();
#pragma unroll
        for (int k = 0; k < 4; ++k) {
            int c = cl + 8 * k;
            int cG = cg * 32 + c;
#pragma unroll
            for (int dw = 0; dw < 2; ++dw) {
                int pl = 2 * w2 + dw;
                int p = prow + pl;
                float d = lsd[pl * 33 + c] * sb[p]
                        + (F1[(size_t)cG * 4096 + p] - F2[(size_t)cG * 4096 + p]);
                acc[k] += fabsf(d);
            }
        }
    }
#pragma unroll
    for (int k = 0; k < 4; ++k) {
        int cG = cg * 32 + cl + 8 * k;
        int f = cG * 1024 + h2 * 32 + w2;
        int n = f >> 7, c = f & 127;
        attn_pk[(size_t)b * 131072 + ((n >> 4) * 4 + (c >> 5)) * 512
                + ((c >> 3) & 3) * 128 + (n & 15) * 8 + (c & 7)] = f2bf(acc[k] * 0.25f);
    }
}

// ---------------- attention pass1: 2 n-tiles/block, fused online (max,sum), z-split
__global__ void __launch_bounds__(256)
attnA_pass1(const unsigned short* __restrict__ attn_pk,
            const unsigned short* __restrict__ incT1, const unsigned short* __restrict__ incT2,
            float* __restrict__ pmax, float* __restrict__ psum)
{
    __shared__ float lm[4][32], ls[4][32];
    int pair = blockIdx.y;
    int b = pair & 3, br = pair >> 2;
    int z = blockIdx.z;
    int tid = threadIdx.x;
    int wave = tid >> 6, lane = tid & 63;
    int n0 = blockIdx.x * 32;
    int q = lane >> 4;
    int col = lane & 15;
    const unsigned short* apk = attn_pk + (size_t)b * 131072 + (size_t)blockIdx.x * 4096 + lane * 8;
    short8 afrA[4], afrB[4];
#pragma unroll
    for (int kc = 0; kc < 4; ++kc) {
        afrA[kc] = *(const short8*)(apk + kc * 512);
        afrB[kc] = *(const short8*)(apk + 2048 + kc * 512);
    }
    const unsigned short* ibp = (br ? incT2 : incT1) + (size_t)b * 524288 + lane * 8;
    short8 bbuf[2][4];
    {
        const unsigned short* brow = ibp + (size_t)(z * 64 + wave * 16) * 2048;
#pragma unroll
        for (int kc = 0; kc < 4; ++kc) bbuf[0][kc] = *(const short8*)(brow + kc * 512);
        brow += 2048;
#pragma unroll
        for (int kc = 0; kc < 4; ++kc) bbuf[1][kc] = *(const short8*)(brow + kc * 512);
    }
    float rmA[4], rsA[4], rmB[4], rsB[4];
#pragma unroll
    for (int r = 0; r < 4; ++r) { rmA[r] = -3.0e38f; rsA[r] = 0.f; rmB[r] = -3.0e38f; rsB[r] = 0.f; }
#pragma unroll
    for (int mt = 0; mt < 16; ++mt) {
        const int cur = mt & 1;
        floatx4 accA = (floatx4){0.f, 0.f, 0.f, 0.f};
        floatx4 accB = (floatx4){0.f, 0.f, 0.f, 0.f};
#pragma unroll
        for (int kc = 0; kc < 4; ++kc) {
            accA = __builtin_amdgcn_mfma_f32_16x16x32_bf16(afrA[kc], bbuf[cur][kc], accA, 0, 0, 0);
            accB = __builtin_amdgcn_mfma_f32_16x16x32_bf16(afrB[kc], bbuf[cur][kc], accB, 0, 0, 0);
        }
        if (mt < 14) {
            const unsigned short* brow = ibp + (size_t)(z * 64 + wave * 16 + mt + 2) * 2048;
#pragma unroll
            for (int kc = 0; kc < 4; ++kc) bbuf[cur][kc] = *(const short8*)(brow + kc * 512);
        }
#pragma unroll
        for (int r = 0; r < 4; ++r) {
            float vA = accA[r];
            float nmA = fmaxf(rmA[r], vA);
            rsA[r] = rsA[r] * __expf(rmA[r] - nmA) + __expf(vA - nmA);
            rmA[r] = nmA;
            float vB = accB[r];
            float nmB = fmaxf(rmB[r], vB);
            rsB[r] = rsB[r] * __expf(rmB[r] - nmB) + __expf(vB - nmB);
            rmB[r] = nmB;
        }
    }
#pragma unroll
    for (int d = 1; d < 16; d <<= 1) {
#pragma unroll
        for (int r = 0; r < 4; ++r) {
            float om = __shfl_xor(rmA[r], d);
            float os = __shfl_xor(rsA[r], d);
            float nm = fmaxf(rmA[r], om);
            rsA[r] = rsA[r] * __expf(rmA[r] - nm) + os * __expf(om - nm);
            rmA[r] = nm;
            om = __shfl_xor(rmB[r], d);
            os = __shfl_xor(rsB[r], d);
            nm = fmaxf(rmB[r], om);
            rsB[r] = rsB[r] * __expf(rmB[r] - nm) + os * __expf(om - nm);
            rmB[r] = nm;
        }
    }
    if (col == 0) {
#pragma unroll
        for (int r = 0; r < 4; ++r) {
            lm[wave][q * 4 + r] = rmA[r];      ls[wave][q * 4 + r] = rsA[r];
            lm[wave][16 + q * 4 + r] = rmB[r]; ls[wave][16 + q * 4 + r] = rsB[r];
        }
    }
    __syncthreads();
    if (tid < 32) {
        float bm = lm[0][tid], bs = ls[0][tid];
        for (int w = 1; w < 4; ++w) {
            float om = lm[w][tid], os = ls[w][tid];
            float nm = fmaxf(bm, om);
            bs = bs * __expf(bm - nm) + os * __expf(om - nm);
            bm = nm;
        }
        pmax[((size_t)pair * 4 + z) * 1024 + n0 + tid] = bm;
        psum[((size_t)pair * 4 + z) * 1024 + n0 + tid] = bs;
    }
}

// ---------------- fused: merge z partials (per thread) + scale attn -> attnS_pk; write mx
__global__ void attnA_scale2(const unsigned short* __restrict__ attn_pk,
                             const float* __restrict__ pmax, const float* __restrict__ psum,
                             float* __restrict__ mx, unsigned short* __restrict__ attnS_pk)
{
    int i = blockIdx.x * 256 + threadIdx.x;   // 1,048,576 (coalesced over packed output)
    int pair = i >> 17;
    int o = i & 131071;
    int j = o & 7, lane = (o >> 3) & 63, ct = (o >> 9) & 7, kcn = o >> 12;
    int c = ct * 16 + (lane & 15);
    int n = kcn * 32 + (lane >> 4) * 8 + j;
    int b = pair & 3;
    float bm = pmax[((size_t)pair * 4) * 1024 + n];
    float bs = psum[((size_t)pair * 4) * 1024 + n];
#pragma unroll
    for (int z = 1; z < 4; ++z) {
        float om = pmax[((size_t)pair * 4 + z) * 1024 + n];
        float os = psum[((size_t)pair * 4 + z) * 1024 + n];
        float nm = fmaxf(bm, om);
        bs = bs * __expf(bm - nm) + os * __expf(om - nm);
        bm = nm;
    }
    if (c == 0) mx[pair * 1024 + n] = bm;
    float rc = 1.f / bs;
    int ii = b * 131072 + ((n >> 4) * 4 + (c >> 5)) * 512
           + ((c >> 3) & 3) * 128 + (n & 15) * 8 + (c & 7);
    attnS_pk[(size_t)i] = f2bf(bf2f(attn_pk[ii]) * rc);
}

// ---------------- attention pass B: 2 m-tiles per wave sharing attnS/attn/mx loads
// (passB4-verified skeleton: 4 waves, 256 threads, manual f2bf pack; grid.x halved)
__global__ void __launch_bounds__(256)
attn_passB6(const unsigned short* __restrict__ attn_pk,
            const unsigned short* __restrict__ attnS_pk,
            const unsigned short* __restrict__ incT1, const unsigned short* __restrict__ incT2,
            const float* __restrict__ mx,
            const float* __restrict__ inc1, const float* __restrict__ inc2,
            float* __restrict__ abuf)
{
    __shared__ unsigned short lp[4][2 * 576];
    __shared__ float lred[2][2048];
    int pair = blockIdx.y;
    int b = pair & 3, br = pair >> 2;
    int tid = threadIdx.x;
    int wv = tid >> 6, lane = tid & 63;
    int q = lane >> 4, col = lane & 15;
    int msub = wv & 1, nh = wv >> 1;
    int mtg0 = blockIdx.x * 4 + msub * 2;       // wave owns m-tiles mtg0, mtg0+1
    const unsigned short* ibp = (br ? incT2 : incT1) + (size_t)b * 524288 + lane * 8;
    short8 bfrA[4], bfrB[4];
#pragma unroll
    for (int kc = 0; kc < 4; ++kc) {
        bfrA[kc] = *(const short8*)(ibp + (size_t)(mtg0 * 4 + kc) * 512);
        bfrB[kc] = *(const short8*)(ibp + (size_t)((mtg0 + 1) * 4 + kc) * 512);
    }
    const float* mxp = mx + pair * 1024 + nh * 512;
    const unsigned short* aspk = attnS_pk + (size_t)pair * 131072 + lane * 8;
    const unsigned short* apk = attn_pk + (size_t)b * 131072 + lane * 8;
    floatx4 oaccA[8], oaccB[8];
#pragma unroll
    for (int ct = 0; ct < 8; ++ct) {
        oaccA[ct] = (floatx4){0.f, 0.f, 0.f, 0.f};
        oaccB[ct] = (floatx4){0.f, 0.f, 0.f, 0.f};
    }
    unsigned short* lwA = lp[wv];
    unsigned short* lwB = lp[wv] + 576;

    short8 arP[2][2][4];
    short8 asP[2][8];
    floatx4 mxq[2][2];
    floatx4 saccA[2][2], saccB[2][2];

    // ---- prologue: nc=0 operands + QK(0) for both m; attn frags for nc=1
#pragma unroll
    for (int t = 0; t < 2; ++t)
#pragma unroll
        for (int kc = 0; kc < 4; ++kc)
            arP[0][t][kc] = *(const short8*)(apk + (size_t)(((nh * 32 + t) * 4 + kc)) * 512);
#pragma unroll
    for (int ct = 0; ct < 8; ++ct)
        asP[0][ct] = *(const short8*)(aspk + (size_t)((nh * 16) * 8 + ct) * 512);
#pragma unroll
    for (int t = 0; t < 2; ++t)
        mxq[0][t] = *(const floatx4*)(mxp + t * 16 + q * 4);
#pragma unroll
    for (int t = 0; t < 2; ++t) {
        floatx4 a = (floatx4){0.f, 0.f, 0.f, 0.f};
        floatx4 bacc = (floatx4){0.f, 0.f, 0.f, 0.f};
#pragma unroll
        for (int kc = 0; kc < 4; ++kc) {
            a    = __builtin_amdgcn_mfma_f32_16x16x32_bf16(arP[0][t][kc], bfrA[kc], a, 0, 0, 0);
            bacc = __builtin_amdgcn_mfma_f32_16x16x32_bf16(arP[0][t][kc], bfrB[kc], bacc, 0, 0, 0);
        }
        saccA[0][t] = a;
        saccB[0][t] = bacc;
    }
#pragma unroll
    for (int t = 0; t < 2; ++t)
#pragma unroll
        for (int kc = 0; kc < 4; ++kc)
            arP[1][t][kc] = *(const short8*)(apk + (size_t)(((nh * 32 + 2 + t) * 4 + kc)) * 512);

#pragma unroll
    for (int nc = 0; nc < 16; ++nc) {
        const int cur = nc & 1, nxt = cur ^ 1;
        // exp + pack + LDS write for both m (sacc computed a full iteration ago)
#pragma unroll
        for (int t = 0; t < 2; ++t) {
            floatx4 mv = mxq[cur][t];
            floatx4 svA = saccA[cur][t];
            unsigned int a01 = (unsigned int)f2bf(__expf(svA[0] - mv[0]))
                             | ((unsigned int)f2bf(__expf(svA[1] - mv[1])) << 16);
            unsigned int a23 = (unsigned int)f2bf(__expf(svA[2] - mv[2]))
                             | ((unsigned int)f2bf(__expf(svA[3] - mv[3])) << 16);
            *(uint2*)&lwA[col * 36 + t * 16 + q * 4] = make_uint2(a01, a23);
            floatx4 svB = saccB[cur][t];
            unsigned int b01 = (unsigned int)f2bf(__expf(svB[0] - mv[0]))
                             | ((unsigned int)f2bf(__expf(svB[1] - mv[1])) << 16);
            unsigned int b23 = (unsigned int)f2bf(__expf(svB[2] - mv[2]))
                             | ((unsigned int)f2bf(__expf(svB[3] - mv[3])) << 16);
            *(uint2*)&lwB[col * 36 + t * 16 + q * 4] = make_uint2(b01, b23);
        }
        // issue next-iteration global loads early (attnS, mx)
        if (nc < 15) {
#pragma unroll
            for (int ct = 0; ct < 8; ++ct)
                asP[nxt][ct] = *(const short8*)(aspk + (size_t)(((nh * 16 + nc + 1) * 8 + ct)) * 512);
#pragma unroll
            for (int t = 0; t < 2; ++t)
                mxq[nxt][t] = *(const floatx4*)(mxp + (nc + 1) * 32 + t * 16 + q * 4);
        }
        short8 pbA = *(const short8*)&lwA[col * 36 + q * 8];
        short8 pbB = *(const short8*)&lwB[col * 36 + q * 8];
        // QK for nc+1, both m (independent of pb -> hides LDS latency)
        if (nc < 15) {
#pragma unroll
            for (int t = 0; t < 2; ++t) {
                floatx4 a = (floatx4){0.f, 0.f, 0.f, 0.f};
                floatx4 bacc = (floatx4){0.f, 0.f, 0.f, 0.f};
#pragma unroll
                for (int kc = 0; kc < 4; ++kc) {
                    a    = __builtin_amdgcn_mfma_f32_16x16x32_bf16(arP[nxt][t][kc], bfrA[kc], a, 0, 0, 0);
                    bacc = __builtin_amdgcn_mfma_f32_16x16x32_bf16(arP[nxt][t][kc], bfrB[kc], bacc, 0, 0, 0);
                }
                saccA[nxt][t] = a;
                saccB[nxt][t] = bacc;
            }
        }
        // attn frags for nc+2 (2 iterations of slack)
        if (nc < 14) {
#pragma unroll
            for (int t = 0; t < 2; ++t)
#pragma unroll
                for (int kc = 0; kc < 4; ++kc)
                    arP[cur][t][kc] = *(const short8*)(apk + (size_t)(((nh * 32 + (nc + 2) * 2 + t) * 4 + kc)) * 512);
        }
        // PV: shared asP feeds both m-tiles
#pragma unroll
        for (int ct = 0; ct < 8; ++ct) {
            oaccA[ct] = __builtin_amdgcn_mfma_f32_16x16x32_bf16(asP[cur][ct], pbA, oaccA[ct], 0, 0, 0);
            oaccB[ct] = __builtin_amdgcn_mfma_f32_16x16x32_bf16(asP[cur][ct], pbB, oaccB[ct], 0, 0, 0);
        }
    }

    // ---- epilogue: two phases (m-tile A then B), LDS-combine nh halves, add residual
    const float* resid = (br ? inc2 : inc1) + (size_t)b * 524288;
    float* op = abuf + ((size_t)(b * 256 + br * 128)) * 4096;
    int mA = mtg0 * 16 + col;       // (blockIdx.x*4 + msub*2) * 16 + col
    int mB = mA + 16;
    if (nh == 1) {
        float* lr = lred[msub];
#pragma unroll
        for (int ct = 0; ct < 8; ++ct)
#pragma unroll
            for (int r = 0; r < 4; ++r)
                lr[(ct * 16 + q * 4 + r) * 16 + col] = oaccA[ct][r];
    }
    __syncthreads();
    if (nh == 0) {
        const float* lr = lred[msub];
#pragma unroll
        for (int ct = 0; ct < 8; ++ct)
#pragma unroll
            for (int r = 0; r < 4; ++r) {
                int row = ct * 16 + q * 4 + r;
                op[(size_t)row * 4096 + mA] = oaccA[ct][r] + lr[row * 16 + col]
                                            + resid[(size_t)row * 4096 + mA];
            }
    }
    __syncthreads();
    if (nh == 1) {
        float* lr = lred[msub];
#pragma unroll
        for (int ct = 0; ct < 8; ++ct)
#pragma unroll
            for (int r = 0; r < 4; ++r)
                lr[(ct * 16 + q * 4 + r) * 16 + col] = oaccB[ct][r];
    }
    __syncthreads();
    if (nh == 0) {
        const float* lr = lred[msub];
#pragma unroll
        for (int ct = 0; ct < 8; ++ct)
#pragma unroll
            for (int r = 0; r < 4; ++r) {
                int row = ct * 16 + q * 4 + r;
                op[(size_t)row * 4096 + mB] = oaccB[ct][r] + lr[row * 16 + col]
                                            + resid[(size_t)row * 4096 + mB];
            }
    }
}

// ---------------- bilinear 2x upsample, half-pixel centers, edge clamp
__global__ void upsample_kernel(const float* __restrict__ in, float* __restrict__ out)
{
    int i = blockIdx.x * 256 + threadIdx.x;
    int x = i & 127, y = (i >> 7) & 127, bc = i >> 14;
    const float* ib = in + (size_t)bc * HW;
    float sy = 0.5f * y - 0.25f;
    float sx = 0.5f * x - 0.25f;
    int y0 = (int)floorf(sy); float ty = sy - y0;
    int x0 = (int)floorf(sx); float tx = sx - x0;
    int y0c = min(max(y0, 0), 63), y1c = min(max(y0 + 1, 0), 63);
    int x0c = min(max(x0, 0), 63), x1c = min(max(x0 + 1, 0), 63);
    float v00 = ib[y0c * 64 + x0c], v01 = ib[y0c * 64 + x1c];
    float v10 = ib[y1c * 64 + x0c], v11 = ib[y1c * 64 + x1c];
    out[i] = (1.f - ty) * ((1.f - tx) * v00 + tx * v01) + ty * ((1.f - tx) * v10 + tx * v11);
}

extern "C" void kernel_launch(void* const* d_in, const int* in_sizes, int n_in,
                              void* d_out, int out_size, void* d_ws, size_t ws_size,
                              hipStream_t stream)
{
    const float* t1       = (const float*)d_in[0];
    const float* t2       = (const float*)d_in[1];
    const float* t1_w     = (const float*)d_in[2];
    const float* t1_b     = (const float*)d_in[3];
    const float* t2_w     = (const float*)d_in[4];
    const float* t2_b     = (const float*)d_in[5];
    const float* df_res_w = (const float*)d_in[6];
    const float* df_res_b = (const float*)d_in[7];
    const float* df_res_s = (const float*)d_in[8];
    const float* df_res_o = (const float*)d_in[9];
    const float* df_b0_w  = (const float*)d_in[10];
    const float* df_b0_b  = (const float*)d_in[11];
    const float* df_b0_s  = (const float*)d_in[12];
    const float* df_b0_o  = (const float*)d_in[13];
    const float* df_b1_w  = (const float*)d_in[14];
    const float* df_b1_b  = (const float*)d_in[15];
    const float* df_b1_s  = (const float*)d_in[16];
    const float* df_b1_o  = (const float*)d_in[17];
    const float* df_fu_w  = (const float*)d_in[18];
    const float* df_fu_b  = (const float*)d_in[19];
    const float* df_fu_s  = (const float*)d_in[20];
    const float* df_fu_o  = (const float*)d_in[21];
    const float* br1_w    = (const float*)d_in[22];
    const float* br1_b    = (const float*)d_in[23];
    const float* br2_w    = (const float*)d_in[24];
    const float* br2_b    = (const float*)d_in[25];
    const float* fu_w     = (const float*)d_in[26];
    const float* fu_b     = (const float*)d_in[27];
    const float* fu_s     = (const float*)d_in[28];
    const float* fu_o     = (const float*)d_in[29];

    float* ws = (float*)d_ws;
    float* res1 = ws;                   // 2,097,152 f  (res1 -> r -> inc1 fp32)
    float* res2 = ws + 2097152;         // 2,097,152 f  (res2 -> b01 -> inc2 fp32)
    float* xbuf = ws + 4194304;         // 4,194,304 f  (x -> dif; fused at +2M)
    float* scr  = ws + 8388608;         // 4,194,304 f  bf16/f32 scratch region
    float* abuf = ws + 12582912;        // 4,194,304 f  concat(a1,a2)
    float* attnS_f = ws + 16777216;     // 524,288 f -> attnS bf16 (packed)
    float* simv = ws + 17301504;        // 16,384 f
    float* mxb  = ws + 17317888;        // 8,192 f

    unsigned short* us     = (unsigned short*)scr;
    unsigned short* wp_b0  = us;                 // 73,728
    unsigned short* wp_b1  = us + 73728;         // 204,800
    unsigned short* wp_br1 = us + 278528;        // 147,456
    unsigned short* wp_br2 = us + 425984;        // 409,600 -> ends 835,584
    unsigned short* xt_r   = us + 851968;        // 2,367,488 -> ends 3,219,456
    unsigned short* xt_dif = us + 3219456;       // 2,367,488 -> ends 5,586,944
    unsigned short* incT1  = us + 5586944;       // 2,097,152 -> ends 7,684,096
    unsigned short* incT2  = us + 851968;        // 2,097,152 (overlays dead xt_r)
    unsigned short* attn_bf= us + 7684096;       // 524,288 -> ends 8,208,384 (f 4,104,192)
    float* scrF = scr;
    float* pmaxb = scrF + 4104192;      // 32,768 f
    float* psumb = scrF + 4136960;      // 32,768 f
    unsigned short* attnS  = (unsigned short*)attnS_f;

    dim3 blk(256);

    // fused: zero padded bf16 conv inputs + prepack all conv weights
    setup_kernel<<<5576, blk, 0, stream>>>((uint4*)xt_r, 591872,
                                           df_b0_w, wp_b0, df_b1_w, wp_b1,
                                           br1_w, wp_br1, br2_w, wp_br2);

    // res1/res2 = 1x1 conv(t1/t2)
    conv1x1_v2<<<dim3(8, 16, 4), blk, 0, stream>>>(t1, t1_w, t1_b, res1, 256, 128, 0, nullptr, nullptr, nullptr, nullptr);
    conv1x1_v2<<<dim3(8, 16, 4), blk, 0, stream>>>(t2, t2_w, t2_b, res2, 256, 128, 0, nullptr, nullptr, nullptr, nullptr);
    sim_kernel<<<4096, blk, 0, stream>>>(res1, res2, simv);
    x_kernel2<<<dim3(128, 4), blk, 0, stream>>>(res1, res2, simv, xbuf);
    simp_kernel3<<<dim3(32, 4, 4), blk, 0, stream>>>(res1, res2, simv, attn_bf);
    // r = stdconv1x1(x) -> res1 (+ bf16 padded chunked copy)
    conv1x1_v2<<<dim3(8, 16, 4), blk, 0, stream>>>(xbuf, df_res_w, df_res_b, res1, 256, 128, 1, df_res_s, df_res_o, nullptr, xt_r);
    // b0 3x3 -> res2[0:64], b1 5x5 -> res2[64:128]
    convk_mfma<3, 64, 1, 4><<<dim3(256, 4), blk, 0, stream>>>(xt_r, wp_b0, df_b0_b, res2, 128, 0, 1, df_b0_s, df_b0_o, nullptr);
    convk_mfma<5, 64, 1, 4><<<dim3(256, 4), blk, 0, stream>>>(xt_r, wp_b1, df_b1_b, res2, 128, 64, 1, df_b1_s, df_b1_o, nullptr);
    // dif = stdconv1x1(b01) + r -> xbuf (+ bf16 padded chunked copy)
    conv1x1_v2<<<dim3(8, 16, 4), blk, 0, stream>>>(res2, df_fu_w, df_fu_b, xbuf, 128, 128, 1, df_fu_s, df_fu_o, res1, xt_dif);
    // inc1/inc2 (fp32 + bf16 B-frag-packed incT)
    convk_mfma<3, 128, 2, 4><<<dim3(256, 4), blk, 0, stream>>>(xt_dif, wp_br1, br1_b, res1, 128, 0, 0, nullptr, nullptr, incT1);
    convk_mfma<5, 128, 2, 4><<<dim3(256, 4), blk, 0, stream>>>(xt_dif, wp_br2, br2_b, res2, 128, 0, 0, nullptr, nullptr, incT2);
    // attention
    attnA_pass1<<<dim3(32, 8, 4), blk, 0, stream>>>(attn_bf, incT1, incT2, pmaxb, psumb);
    attnA_scale2<<<4096, blk, 0, stream>>>(attn_bf, pmaxb, psumb, mxb, attnS);
    attn_passB6<<<dim3(64, 8), blk, 0, stream>>>(attn_bf, attnS, incT1, incT2, mxb, res1, res2, abuf);
    // fused = stdconv1x1(concat(a1,a2)) + dif
    float* dif = xbuf;
    float* fused = xbuf + 2097152;
    conv1x1_v2<<<dim3(8, 16, 4), blk, 0, stream>>>(abuf, fu_w, fu_b, fused, 256, 128, 1, fu_s, fu_o, dif, nullptr);
    // bilinear 2x upsample -> d_out
    upsample_kernel<<<32768, blk, 0, stream>>>(fused, (float*)d_out);
}

// Round 8
// 495.043 us; speedup vs baseline: 1.1076x; 1.1076x over previous
//
#include <hip/hip_runtime.h>
#include <math.h>

#define HW 4096   // 64*64

typedef __attribute__((ext_vector_type(8))) short short8;
typedef __attribute__((ext_vector_type(4))) float floatx4;
typedef __attribute__((ext_vector_type(2))) float floatx2;

__device__ inline unsigned short f2bf(float f) {
    unsigned int u = __float_as_uint(f);
    unsigned int r = (u + 0x7fffu + ((u >> 16) & 1u)) >> 16;
    return (unsigned short)r;
}
__device__ inline float bf2f(unsigned short u) {
    return __uint_as_float(((unsigned int)u) << 16);
}

// Fragment-pack index helpers.
// A-frag pack of matrix M[R rows][K cols]: element (r,k) at
//   tile(r>>4, k>>5)*512 + ((k>>3)&3)*128 + (r&15)*8 + (k&7); wave loads base + tile*512 + lane*8.
// xt (conv activations) layout: [b][ci>>3][row(68)][col(68)][ci&7].

// ---------------- fused setup: zero padded xt + 6 weight prepacks
__device__ inline void prepack_dev(const float* __restrict__ w, unsigned short* __restrict__ wp,
                                   int CO, int CI, int KK, int i)
{
    if (i >= CO * CI * KK) return;
    int ci = i % CI;
    int t = i / CI;
    int co = t % CO;
    int kk = t / CO;
    int ti = (kk * (CO >> 4) + (co >> 4)) * (CI >> 5) + (ci >> 5);
    wp[(size_t)ti * 512 + ((ci >> 3) & 3) * 128 + (co & 15) * 8 + (ci & 7)]
        = f2bf(w[(co * CI + ci) * KK + kk]);
}

__global__ void setup_kernel(uint4* __restrict__ zp, int zn,
                             const float* __restrict__ w0, unsigned short* __restrict__ wp0,
                             const float* __restrict__ w1, unsigned short* __restrict__ wp1,
                             const float* __restrict__ w2, unsigned short* __restrict__ wp2,
                             const float* __restrict__ w3, unsigned short* __restrict__ wp3,
                             const float* __restrict__ w4, unsigned short* __restrict__ wp4,
                             const float* __restrict__ w5, unsigned short* __restrict__ wp5)
{
    int bx = blockIdx.x, tid = threadIdx.x;
    if (bx < 2312) {
        int i = bx * 256 + tid;
        if (i < zn) zp[i] = make_uint4(0u, 0u, 0u, 0u);
    } else if (bx < 2600) {
        prepack_dev(w0, wp0, 64, 128, 9,  (bx - 2312) * 256 + tid);
    } else if (bx < 3400) {
        prepack_dev(w1, wp1, 64, 128, 25, (bx - 2600) * 256 + tid);
    } else if (bx < 3976) {
        prepack_dev(w2, wp2, 128, 128, 9, (bx - 3400) * 256 + tid);
    } else if (bx < 5576) {
        prepack_dev(w3, wp3, 128, 128, 25,(bx - 3976) * 256 + tid);
    } else if (bx < 5704) {
        prepack_dev(w4, wp4, 128, 256, 1, (bx - 5576) * 256 + tid);
    } else {
        prepack_dev(w5, wp5, 128, 256, 1, (bx - 5704) * 256 + tid);
    }
}

// ---------------- pack fp32 [b][256ci][4096px] -> A-frag-packed bf16 (px rows, ci k)
__global__ void packX(const float* __restrict__ in, unsigned short* __restrict__ out)
{
    int i = blockIdx.x * 256 + threadIdx.x;    // 4,194,304
    int b = i >> 20;
    int j = i & 1048575;
    int ci = j >> 12, px = j & 4095;
    out[(size_t)b * 1048576 + ((size_t)((px >> 4) * 8 + (ci >> 5))) * 512
        + ((ci >> 3) & 3) * 128 + (px & 15) * 8 + (ci & 7)] = f2bf(in[i]);
}

// ---------------- 1x1 conv (CI=256, CO=128) as bf16 MFMA GEMM: out = W*X + b
__global__ void __launch_bounds__(256)
gemm1x1_t(const unsigned short* __restrict__ Xpk, const unsigned short* __restrict__ Wpk,
          const float* __restrict__ bias, float* __restrict__ out)
{
    int tid = threadIdx.x;
    int wv = tid >> 6, lane = tid & 63;
    int q = lane >> 4, n = lane & 15;
    int pxb = blockIdx.x;                       // 256 px-tiles of 16
    int b = blockIdx.y;
    int co0 = wv * 32;
    const unsigned short* apk = Xpk + (size_t)b * 1048576 + (size_t)pxb * 8 * 512 + lane * 8;
    const unsigned short* wpk = Wpk + (size_t)(co0 >> 4) * 8 * 512 + lane * 8;
    floatx4 acc0 = (floatx4){0.f, 0.f, 0.f, 0.f};
    floatx4 acc1 = (floatx4){0.f, 0.f, 0.f, 0.f};
#pragma unroll
    for (int kc = 0; kc < 8; ++kc) {
        short8 a  = *(const short8*)(apk + kc * 512);
        short8 b0 = *(const short8*)(wpk + kc * 512);
        short8 b1 = *(const short8*)(wpk + 8 * 512 + kc * 512);
        acc0 = __builtin_amdgcn_mfma_f32_16x16x32_bf16(a, b0, acc0, 0, 0, 0);
        acc1 = __builtin_amdgcn_mfma_f32_16x16x32_bf16(a, b1, acc1, 0, 0, 0);
    }
    int px0 = pxb * 16 + q * 4;
#pragma unroll
    for (int nt = 0; nt < 2; ++nt) {
        int co = co0 + nt * 16 + n;
        float bi = bias[co];
        floatx4 v = nt ? acc1 : acc0;
        v[0] += bi; v[1] += bi; v[2] += bi; v[3] += bi;
        *(floatx4*)(out + ((size_t)(b * 128 + co)) * 4096 + px0) = v;
    }
}

// ---------------- 1x1 conv: 2 px/thread (float2), 8 co/thread, weights in LDS
__global__ void __launch_bounds__(256)
conv1x1_v2(const float* __restrict__ in, const float* __restrict__ w,
           const float* __restrict__ bias, float* __restrict__ out,
           int CI, int CO, int do_affine,
           const float* __restrict__ s, const float* __restrict__ o,
           const float* __restrict__ addbuf, unsigned short* __restrict__ xt)
{
    __shared__ float wl[2048];
    int tid = threadIdx.x;
    int c0 = blockIdx.y * 8;
    int b = blockIdx.z;
    for (int i = tid; i < CI * 8; i += 256) {
        int k = i & 7, ci = i >> 3;
        wl[i] = w[(c0 + k) * CI + ci];
    }
    __syncthreads();
    int m = blockIdx.x * 512 + tid * 2;
    floatx2 acc[8];
#pragma unroll
    for (int k = 0; k < 8; ++k) {
        float bv = bias[c0 + k];
        acc[k] = (floatx2){bv, bv};
    }
    const float* inb = in + (size_t)b * CI * HW + m;
#pragma unroll 4
    for (int ci = 0; ci < CI; ++ci) {
        floatx2 v = *(const floatx2*)(inb + (size_t)ci * HW);
#pragma unroll
        for (int k = 0; k < 8; ++k) acc[k] += wl[ci * 8 + k] * v;
    }
#pragma unroll
    for (int k = 0; k < 8; ++k) {
        floatx2 v = acc[k];
        if (do_affine) {
            float sc = s[c0 + k], of = o[c0 + k];
            v[0] = fmaxf(v[0], 0.f) * sc + of;
            v[1] = fmaxf(v[1], 0.f) * sc + of;
        }
        size_t oidx = ((size_t)(b * CO + c0 + k)) * HW + m;
        if (addbuf) v += *(const floatx2*)(addbuf + oidx);
        *(floatx2*)(out + oidx) = v;
        acc[k] = v;
    }
    if (xt) {
#pragma unroll
        for (int r = 0; r < 2; ++r) {
            int mm = m + r;
            union { unsigned short u16[8]; uint4 q; } pk;
#pragma unroll
            for (int k = 0; k < 8; ++k) pk.u16[k] = f2bf(acc[k][r]);
            int h = mm >> 6, wc = mm & 63;
            // chunked layout [b][c0>>3][row][col][8]
            *(uint4*)(xt + ((size_t)(b * 16 + (c0 >> 3)) * 4624 + (h + 2) * 68 + (wc + 2)) * 8) = pk.q;
        }
    }
}

// ---------------- KxK conv as implicit-GEMM bf16 MFMA, m-split MS for occupancy
template<int K, int CO, int NB, int MS>
__global__ void __launch_bounds__(256)
convk_mfma(const unsigned short* __restrict__ xt, const unsigned short* __restrict__ wp,
           const float* __restrict__ bias, float* __restrict__ out,
           int OB, int co_off, int do_affine,
           const float* __restrict__ s, const float* __restrict__ o,
           unsigned short* __restrict__ incT)
{
    constexpr int CI = 128;
    constexpr int PAD = K / 2;
    constexpr int RO = 2 - PAD;
    constexpr int MT = 4 / MS;
    constexpr int CO16 = CO >> 4;
    constexpr int CI32 = CI >> 5;
    int tid = threadIdx.x;
    int wave = tid >> 6, lane = tid & 63;
    int h = blockIdx.x / MS, msb = blockIdx.x % MS;
    int b = blockIdx.y;
    int co0 = wave * 16 * NB;
    int n = lane & 15, q = lane >> 4;
    floatx4 acc[MT][NB];
#pragma unroll
    for (int mt = 0; mt < MT; ++mt)
#pragma unroll
        for (int nt = 0; nt < NB; ++nt) acc[mt][nt] = (floatx4){0.f, 0.f, 0.f, 0.f};

    const unsigned short* xb = xt + (size_t)(b * 16) * 4624 * 8;
    int mbase = msb * MT * 16;
    for (int ci0 = 0; ci0 < CI; ci0 += 32) {
#pragma unroll
        for (int kh = 0; kh < K; ++kh) {
            const unsigned short* xrow = xb + (size_t)(((ci0 >> 3) + q) * 4624 + (h + kh + RO) * 68 + RO) * 8;
            const unsigned short* wkh = wp + ((size_t)(kh * K) * CO16 * CI32 + (ci0 >> 5)) * 512 + lane * 8;
#pragma unroll
            for (int kw = 0; kw < K; ++kw) {
                short8 bfr[NB];
#pragma unroll
                for (int nt = 0; nt < NB; ++nt)
                    bfr[nt] = *(const short8*)(wkh + (size_t)((kw * CO16 + (co0 >> 4) + nt) * CI32) * 512);
#pragma unroll
                for (int mt = 0; mt < MT; ++mt) {
                    short8 afr = *(const short8*)(xrow + (mbase + mt * 16 + n + kw) * 8);
#pragma unroll
                    for (int nt = 0; nt < NB; ++nt)
                        acc[mt][nt] = __builtin_amdgcn_mfma_f32_16x16x32_bf16(afr, bfr[nt], acc[mt][nt], 0, 0, 0);
                }
            }
        }
    }
    int px0 = h * 64 + mbase + q * 4;
#pragma unroll
    for (int nt = 0; nt < NB; ++nt) {
        int co = co0 + nt * 16 + n;
        float bi = bias[co];
        float sc = do_affine ? s[co] : 1.f;
        float of = do_affine ? o[co] : 0.f;
        float* ob = out + ((size_t)(b * OB + co_off + co)) * HW;
        unsigned short* tb = incT ? incT + (size_t)b * 524288 : nullptr;
        int cpart = (co >> 5) * 512 + ((co >> 3) & 3) * 128 + (co & 7);
#pragma unroll
        for (int mt = 0; mt < MT; ++mt)
#pragma unroll
            for (int r = 0; r < 4; ++r) {
                int px = px0 + mt * 16 + r;
                float v = acc[mt][nt][r] + bi;
                if (do_affine) v = fmaxf(v, 0.f) * sc + of;
                ob[px] = v;
                if (incT) tb[(size_t)((px >> 4) * 2048 + cpart + (px & 15) * 8)] = f2bf(v);
            }
    }
}

// ---------------- cosine similarity over groups of 128 consecutive floats
__global__ void sim_kernel(const float* __restrict__ r1, const float* __restrict__ r2,
                           float* __restrict__ sim)
{
    int gw = blockIdx.x * 4 + (threadIdx.x >> 6);
    int lane = threadIdx.x & 63;
    int b = gw >> 12, n = gw & 4095;
    const float* p1 = r1 + (size_t)b * 524288 + (size_t)n * 128;
    const float* p2 = r2 + (size_t)b * 524288 + (size_t)n * 128;
    float a0 = p1[lane], a1 = p1[lane + 64];
    float b0 = p2[lane], b1 = p2[lane + 64];
    float dot = a0 * b0 + a1 * b1;
    float n1 = a0 * a0 + a1 * a1;
    float n2 = b0 * b0 + b1 * b1;
    for (int m = 32; m; m >>= 1) {
        dot += __shfl_xor(dot, m);
        n1  += __shfl_xor(n1, m);
        n2  += __shfl_xor(n2, m);
    }
    if (lane == 0) sim[b * 4096 + n] = dot / fmaxf(sqrtf(n1) * sqrtf(n2), 1e-8f);
}

// ---------------- x = concat(dif1, dif2): LDS-transposed, coalesced
__global__ void __launch_bounds__(256)
x_kernel2(const float* __restrict__ r1, const float* __restrict__ r2,
          const float* __restrict__ sim, float* __restrict__ xo)
{
    __shared__ float ls1[32 * 129], ls2[32 * 129];
    int b = blockIdx.y, p0 = blockIdx.x * 32, tid = threadIdx.x;
    const float* F1 = r1 + (size_t)b * 524288;
    const float* F2 = r2 + (size_t)b * 524288;
    for (int i = tid; i < 32 * 128; i += 256) {
        int p = i >> 7, c = i & 127;
        ls1[p * 129 + c] = F1[p0 * 128 + i];
        ls2[p * 129 + c] = F2[p0 * 128 + i];
    }
    __syncthreads();
    for (int j = tid; j < 256 * 32; j += 256) {
        int p = j & 31, cc = j >> 5;
        int c = cc & 127;
        float sv = sim[b * 4096 + p0 + p];
        const float* F = (cc & 128) ? F2 : F1;
        float t1v = ((cc & 128) ? ls2 : ls1)[p * 129 + c];
        xo[(size_t)b * 1048576 + (size_t)cc * 4096 + p0 + p] = t1v * (1.f - sv) + F[(size_t)c * 4096 + p0 + p];
    }
}

// ---------------- attn = avgpool2(|sim1-sim2|) -> A-frag-packed bf16, channel-split
__global__ void __launch_bounds__(256)
simp_kernel3(const float* __restrict__ r1, const float* __restrict__ r2,
             const float* __restrict__ sim, unsigned short* __restrict__ attn_pk)
{
    __shared__ float lsd[64 * 33];
    int b = blockIdx.y, h2 = blockIdx.x, cg = blockIdx.z, tid = threadIdx.x;
    const float* F1 = r1 + (size_t)b * 524288;
    const float* F2 = r2 + (size_t)b * 524288;
    const float* sb = sim + b * 4096;
    int w2 = tid & 31, cl = tid >> 5;
    float acc[4] = {};
    for (int dh = 0; dh < 2; ++dh) {
        int prow = h2 * 128 + dh * 64;
        __syncthreads();
        for (int i = tid; i < 64 * 32; i += 256) {
            int p = i >> 5, c = i & 31;
            size_t gi = (size_t)(prow + p) * 128 + cg * 32 + c;
            lsd[p * 33 + c] = F1[gi] - F2[gi];
        }
        __syncthreads();
#pragma unroll
        for (int k = 0; k < 4; ++k) {
            int c = cl + 8 * k;
            int cG = cg * 32 + c;
#pragma unroll
            for (int dw = 0; dw < 2; ++dw) {
                int pl = 2 * w2 + dw;
                int p = prow + pl;
                float d = lsd[pl * 33 + c] * sb[p]
                        + (F1[(size_t)cG * 4096 + p] - F2[(size_t)cG * 4096 + p]);
                acc[k] += fabsf(d);
            }
        }
    }
#pragma unroll
    for (int k = 0; k < 4; ++k) {
        int cG = cg * 32 + cl + 8 * k;
        int f = cG * 1024 + h2 * 32 + w2;
        int n = f >> 7, c = f & 127;
        attn_pk[(size_t)b * 131072 + ((n >> 4) * 4 + (c >> 5)) * 512
                + ((c >> 3) & 3) * 128 + (n & 15) * 8 + (c & 7)] = f2bf(acc[k] * 0.25f);
    }
}

// ---------------- attention pass1: 2 n-tiles/block, fused online (max,sum), z-split
__global__ void __launch_bounds__(256)
attnA_pass1(const unsigned short* __restrict__ attn_pk,
            const unsigned short* __restrict__ incT1, const unsigned short* __restrict__ incT2,
            float* __restrict__ pmax, float* __restrict__ psum)
{
    __shared__ float lm[4][32], ls[4][32];
    int pair = blockIdx.y;
    int b = pair & 3, br = pair >> 2;
    int z = blockIdx.z;
    int tid = threadIdx.x;
    int wave = tid >> 6, lane = tid & 63;
    int n0 = blockIdx.x * 32;
    int q = lane >> 4;
    int col = lane & 15;
    const unsigned short* apk = attn_pk + (size_t)b * 131072 + (size_t)blockIdx.x * 4096 + lane * 8;
    short8 afrA[4], afrB[4];
#pragma unroll
    for (int kc = 0; kc < 4; ++kc) {
        afrA[kc] = *(const short8*)(apk + kc * 512);
        afrB[kc] = *(const short8*)(apk + 2048 + kc * 512);
    }
    const unsigned short* ibp = (br ? incT2 : incT1) + (size_t)b * 524288 + lane * 8;
    short8 bbuf[2][4];
    {
        const unsigned short* brow = ibp + (size_t)(z * 64 + wave * 16) * 2048;
#pragma unroll
        for (int kc = 0; kc < 4; ++kc) bbuf[0][kc] = *(const short8*)(brow + kc * 512);
        brow += 2048;
#pragma unroll
        for (int kc = 0; kc < 4; ++kc) bbuf[1][kc] = *(const short8*)(brow + kc * 512);
    }
    float rmA[4], rsA[4], rmB[4], rsB[4];
#pragma unroll
    for (int r = 0; r < 4; ++r) { rmA[r] = -3.0e38f; rsA[r] = 0.f; rmB[r] = -3.0e38f; rsB[r] = 0.f; }
#pragma unroll
    for (int mt = 0; mt < 16; ++mt) {
        const int cur = mt & 1;
        floatx4 accA = (floatx4){0.f, 0.f, 0.f, 0.f};
        floatx4 accB = (floatx4){0.f, 0.f, 0.f, 0.f};
#pragma unroll
        for (int kc = 0; kc < 4; ++kc) {
            accA = __builtin_amdgcn_mfma_f32_16x16x32_bf16(afrA[kc], bbuf[cur][kc], accA, 0, 0, 0);
            accB = __builtin_amdgcn_mfma_f32_16x16x32_bf16(afrB[kc], bbuf[cur][kc], accB, 0, 0, 0);
        }
        if (mt < 14) {
            const unsigned short* brow = ibp + (size_t)(z * 64 + wave * 16 + mt + 2) * 2048;
#pragma unroll
            for (int kc = 0; kc < 4; ++kc) bbuf[cur][kc] = *(const short8*)(brow + kc * 512);
        }
#pragma unroll
        for (int r = 0; r < 4; ++r) {
            float vA = accA[r];
            float nmA = fmaxf(rmA[r], vA);
            rsA[r] = rsA[r] * __expf(rmA[r] - nmA) + __expf(vA - nmA);
            rmA[r] = nmA;
            float vB = accB[r];
            float nmB = fmaxf(rmB[r], vB);
            rsB[r] = rsB[r] * __expf(rmB[r] - nmB) + __expf(vB - nmB);
            rmB[r] = nmB;
        }
    }
#pragma unroll
    for (int d = 1; d < 16; d <<= 1) {
#pragma unroll
        for (int r = 0; r < 4; ++r) {
            float om = __shfl_xor(rmA[r], d);
            float os = __shfl_xor(rsA[r], d);
            float nm = fmaxf(rmA[r], om);
            rsA[r] = rsA[r] * __expf(rmA[r] - nm) + os * __expf(om - nm);
            rmA[r] = nm;
            om = __shfl_xor(rmB[r], d);
            os = __shfl_xor(rsB[r], d);
            nm = fmaxf(rmB[r], om);
            rsB[r] = rsB[r] * __expf(rmB[r] - nm) + os * __expf(om - nm);
            rmB[r] = nm;
        }
    }
    if (col == 0) {
#pragma unroll
        for (int r = 0; r < 4; ++r) {
            lm[wave][q * 4 + r] = rmA[r];      ls[wave][q * 4 + r] = rsA[r];
            lm[wave][16 + q * 4 + r] = rmB[r]; ls[wave][16 + q * 4 + r] = rsB[r];
        }
    }
    __syncthreads();
    if (tid < 32) {
        float bm = lm[0][tid], bs = ls[0][tid];
        for (int w = 1; w < 4; ++w) {
            float om = lm[w][tid], os = ls[w][tid];
            float nm = fmaxf(bm, om);
            bs = bs * __expf(bm - nm) + os * __expf(om - nm);
            bm = nm;
        }
        pmax[((size_t)pair * 4 + z) * 1024 + n0 + tid] = bm;
        psum[((size_t)pair * 4 + z) * 1024 + n0 + tid] = bs;
    }
}

// ---------------- fused: merge z partials (per thread) + scale attn -> attnS_pk; write mx
__global__ void attnA_scale2(const unsigned short* __restrict__ attn_pk,
                             const float* __restrict__ pmax, const float* __restrict__ psum,
                             float* __restrict__ mx, unsigned short* __restrict__ attnS_pk)
{
    int i = blockIdx.x * 256 + threadIdx.x;   // 1,048,576 (coalesced over packed output)
    int pair = i >> 17;
    int o = i & 131071;
    int j = o & 7, lane = (o >> 3) & 63, ct = (o >> 9) & 7, kcn = o >> 12;
    int c = ct * 16 + (lane & 15);
    int n = kcn * 32 + (lane >> 4) * 8 + j;
    int b = pair & 3;
    float bm = pmax[((size_t)pair * 4) * 1024 + n];
    float bs = psum[((size_t)pair * 4) * 1024 + n];
#pragma unroll
    for (int z = 1; z < 4; ++z) {
        float om = pmax[((size_t)pair * 4 + z) * 1024 + n];
        float os = psum[((size_t)pair * 4 + z) * 1024 + n];
        float nm = fmaxf(bm, om);
        bs = bs * __expf(bm - nm) + os * __expf(om - nm);
        bm = nm;
    }
    if (c == 0) mx[pair * 1024 + n] = bm;
    float rc = 1.f / bs;
    int ii = b * 131072 + ((n >> 4) * 4 + (c >> 5)) * 512
           + ((c >> 3) & 3) * 128 + (n & 15) * 8 + (c & 7);
    attnS_pk[(size_t)i] = f2bf(bf2f(attn_pk[ii]) * rc);
}

// ---------------- attention pass B: deep software pipeline, LDS-combined epilogue
// (R6-harness-verified passB4, verbatim)
__global__ void __launch_bounds__(256)
attn_passB4(const unsigned short* __restrict__ attn_pk,
            const unsigned short* __restrict__ attnS_pk,
            const unsigned short* __restrict__ incT1, const unsigned short* __restrict__ incT2,
            const float* __restrict__ mx,
            const float* __restrict__ inc1, const float* __restrict__ inc2,
            float* __restrict__ abuf)
{
    __shared__ unsigned short lp[4][16 * 36];
    __shared__ float lred[2][2048];
    int pair = blockIdx.y;
    int b = pair & 3, br = pair >> 2;
    int tid = threadIdx.x;
    int wv = tid >> 6, lane = tid & 63;
    int q = lane >> 4, col = lane & 15;
    int msub = wv & 1, nh = wv >> 1;
    int m0 = blockIdx.x * 32 + msub * 16;
    int mtg = m0 >> 4;
    const unsigned short* ibp = (br ? incT2 : incT1) + (size_t)b * 524288 + lane * 8;
    short8 bfrS[4];
#pragma unroll
    for (int kc = 0; kc < 4; ++kc)
        bfrS[kc] = *(const short8*)(ibp + (size_t)(mtg * 4 + kc) * 512);
    const float* mxp = mx + pair * 1024 + nh * 512;
    const unsigned short* aspk = attnS_pk + (size_t)pair * 131072 + lane * 8;
    const unsigned short* apk = attn_pk + (size_t)b * 131072 + lane * 8;
    floatx4 oacc[8];
#pragma unroll
    for (int ct = 0; ct < 8; ++ct) oacc[ct] = (floatx4){0.f, 0.f, 0.f, 0.f};
    unsigned short* lw = lp[wv];

    short8 arP[2][2][4];
    short8 asP[2][8];
    floatx4 mxq[2][2];
    floatx4 sacc[2][2];

#pragma unroll
    for (int t = 0; t < 2; ++t)
#pragma unroll
        for (int kc = 0; kc < 4; ++kc)
            arP[0][t][kc] = *(const short8*)(apk + (size_t)(((nh * 32 + t) * 4 + kc)) * 512);
#pragma unroll
    for (int ct = 0; ct < 8; ++ct)
        asP[0][ct] = *(const short8*)(aspk + (size_t)((nh * 16) * 8 + ct) * 512);
#pragma unroll
    for (int t = 0; t < 2; ++t)
        mxq[0][t] = *(const floatx4*)(mxp + t * 16 + q * 4);
#pragma unroll
    for (int t = 0; t < 2; ++t) {
        floatx4 a = (floatx4){0.f, 0.f, 0.f, 0.f};
#pragma unroll
        for (int kc = 0; kc < 4; ++kc)
            a = __builtin_amdgcn_mfma_f32_16x16x32_bf16(arP[0][t][kc], bfrS[kc], a, 0, 0, 0);
        sacc[0][t] = a;
    }
#pragma unroll
    for (int t = 0; t < 2; ++t)
#pragma unroll
        for (int kc = 0; kc < 4; ++kc)
            arP[1][t][kc] = *(const short8*)(apk + (size_t)(((nh * 32 + 2 + t) * 4 + kc)) * 512);

#pragma unroll
    for (int nc = 0; nc < 16; ++nc) {
        const int cur = nc & 1, nxt = cur ^ 1;
#pragma unroll
        for (int t = 0; t < 2; ++t) {
            floatx4 sv = sacc[cur][t];
            floatx4 mv = mxq[cur][t];
            unsigned int p01 = (unsigned int)f2bf(__expf(sv[0] - mv[0]))
                             | ((unsigned int)f2bf(__expf(sv[1] - mv[1])) << 16);
            unsigned int p23 = (unsigned int)f2bf(__expf(sv[2] - mv[2]))
                             | ((unsigned int)f2bf(__expf(sv[3] - mv[3])) << 16);
            *(uint2*)&lw[col * 36 + t * 16 + q * 4] = make_uint2(p01, p23);
        }
        if (nc < 15) {
#pragma unroll
            for (int ct = 0; ct < 8; ++ct)
                asP[nxt][ct] = *(const short8*)(aspk + (size_t)(((nh * 16 + nc + 1) * 8 + ct)) * 512);
#pragma unroll
            for (int t = 0; t < 2; ++t)
                mxq[nxt][t] = *(const floatx4*)(mxp + (nc + 1) * 32 + t * 16 + q * 4);
        }
        short8 pb = *(const short8*)&lw[col * 36 + q * 8];
        if (nc < 15) {
#pragma unroll
            for (int t = 0; t < 2; ++t) {
                floatx4 a = (floatx4){0.f, 0.f, 0.f, 0.f};
#pragma unroll
                for (int kc = 0; kc < 4; ++kc)
                    a = __builtin_amdgcn_mfma_f32_16x16x32_bf16(arP[nxt][t][kc], bfrS[kc], a, 0, 0, 0);
                sacc[nxt][t] = a;
            }
        }
        if (nc < 14) {
#pragma unroll
            for (int t = 0; t < 2; ++t)
#pragma unroll
                for (int kc = 0; kc < 4; ++kc)
                    arP[cur][t][kc] = *(const short8*)(apk + (size_t)(((nh * 32 + (nc + 2) * 2 + t) * 4 + kc)) * 512);
        }
#pragma unroll
        for (int ct = 0; ct < 8; ++ct)
            oacc[ct] = __builtin_amdgcn_mfma_f32_16x16x32_bf16(asP[cur][ct], pb, oacc[ct], 0, 0, 0);
    }

    if (nh == 1) {
        float* lr = lred[msub];
#pragma unroll
        for (int ct = 0; ct < 8; ++ct)
#pragma unroll
            for (int r = 0; r < 4; ++r)
                lr[(ct * 16 + q * 4 + r) * 16 + col] = oacc[ct][r];
    }
    __syncthreads();
    if (nh == 0) {
        const float* lr = lred[msub];
        const float* resid = (br ? inc2 : inc1) + (size_t)b * 524288;
        float* op = abuf + ((size_t)(b * 256 + br * 128)) * 4096;
        int m = m0 + col;
#pragma unroll
        for (int ct = 0; ct < 8; ++ct)
#pragma unroll
            for (int r = 0; r < 4; ++r) {
                int row = ct * 16 + q * 4 + r;
                op[(size_t)row * 4096 + m] = oacc[ct][r] + lr[row * 16 + col]
                                           + resid[(size_t)row * 4096 + m];
            }
    }
}

// ---------------- bilinear 2x upsample, half-pixel centers, edge clamp
__global__ void upsample_kernel(const float* __restrict__ in, float* __restrict__ out)
{
    int i = blockIdx.x * 256 + threadIdx.x;
    int x = i & 127, y = (i >> 7) & 127, bc = i >> 14;
    const float* ib = in + (size_t)bc * HW;
    float sy = 0.5f * y - 0.25f;
    float sx = 0.5f * x - 0.25f;
    int y0 = (int)floorf(sy); float ty = sy - y0;
    int x0 = (int)floorf(sx); float tx = sx - x0;
    int y0c = min(max(y0, 0), 63), y1c = min(max(y0 + 1, 0), 63);
    int x0c = min(max(x0, 0), 63), x1c = min(max(x0 + 1, 0), 63);
    float v00 = ib[y0c * 64 + x0c], v01 = ib[y0c * 64 + x1c];
    float v10 = ib[y1c * 64 + x0c], v11 = ib[y1c * 64 + x1c];
    out[i] = (1.f - ty) * ((1.f - tx) * v00 + tx * v01) + ty * ((1.f - tx) * v10 + tx * v11);
}

extern "C" void kernel_launch(void* const* d_in, const int* in_sizes, int n_in,
                              void* d_out, int out_size, void* d_ws, size_t ws_size,
                              hipStream_t stream)
{
    const float* t1       = (const float*)d_in[0];
    const float* t2       = (const float*)d_in[1];
    const float* t1_w     = (const float*)d_in[2];
    const float* t1_b     = (const float*)d_in[3];
    const float* t2_w     = (const float*)d_in[4];
    const float* t2_b     = (const float*)d_in[5];
    const float* df_res_w = (const float*)d_in[6];
    const float* df_res_b = (const float*)d_in[7];
    const float* df_res_s = (const float*)d_in[8];
    const float* df_res_o = (const float*)d_in[9];
    const float* df_b0_w  = (const float*)d_in[10];
    const float* df_b0_b  = (const float*)d_in[11];
    const float* df_b0_s  = (const float*)d_in[12];
    const float* df_b0_o  = (const float*)d_in[13];
    const float* df_b1_w  = (const float*)d_in[14];
    const float* df_b1_b  = (const float*)d_in[15];
    const float* df_b1_s  = (const float*)d_in[16];
    const float* df_b1_o  = (const float*)d_in[17];
    const float* df_fu_w  = (const float*)d_in[18];
    const float* df_fu_b  = (const float*)d_in[19];
    const float* df_fu_s  = (const float*)d_in[20];
    const float* df_fu_o  = (const float*)d_in[21];
    const float* br1_w    = (const float*)d_in[22];
    const float* br1_b    = (const float*)d_in[23];
    const float* br2_w    = (const float*)d_in[24];
    const float* br2_b    = (const float*)d_in[25];
    const float* fu_w     = (const float*)d_in[26];
    const float* fu_b     = (const float*)d_in[27];
    const float* fu_s     = (const float*)d_in[28];
    const float* fu_o     = (const float*)d_in[29];

    float* ws = (float*)d_ws;
    float* res1 = ws;                   // 2,097,152 f  (res1 -> r -> inc1 fp32)
    float* res2 = ws + 2097152;         // 2,097,152 f  (res2 -> b01 -> inc2 fp32)
    float* xbuf = ws + 4194304;         // 4,194,304 f  (t1pk/t2pk early; x -> dif; fused at +2M)
    float* scr  = ws + 8388608;         // 4,194,304 f  bf16/f32 scratch region
    float* abuf = ws + 12582912;        // 4,194,304 f  concat(a1,a2)
    float* attnS_f = ws + 16777216;     // 524,288 f -> wp_t1/t2 early; attnS bf16 (packed)
    float* simv = ws + 17301504;        // 16,384 f
    float* mxb  = ws + 17317888;        // 8,192 f

    unsigned short* us     = (unsigned short*)scr;
    unsigned short* wp_b0  = us;                 // 73,728
    unsigned short* wp_b1  = us + 73728;         // 204,800
    unsigned short* wp_br1 = us + 278528;        // 147,456
    unsigned short* wp_br2 = us + 425984;        // 409,600 -> ends 835,584
    unsigned short* xt_r   = us + 851968;        // 2,367,488 -> ends 3,219,456
    unsigned short* xt_dif = us + 3219456;       // 2,367,488 -> ends 5,586,944
    unsigned short* incT1  = us + 5586944;       // 2,097,152 -> ends 7,684,096
    unsigned short* incT2  = us + 851968;        // 2,097,152 (overlays dead xt_r)
    unsigned short* attn_bf= us + 7684096;       // 524,288 -> ends 8,208,384 (f 4,104,192)
    float* scrF = scr;
    float* pmaxb = scrF + 4104192;      // 32,768 f
    float* psumb = scrF + 4136960;      // 32,768 f
    unsigned short* attnS  = (unsigned short*)attnS_f;
    // early-phase overlays (dead before their regions' later use)
    unsigned short* wp_t1 = (unsigned short*)attnS_f;        // 32,768 sh (dead before attnS)
    unsigned short* wp_t2 = wp_t1 + 32768;                   // 32,768 sh
    unsigned short* t1pk  = (unsigned short*)xbuf;           // 4,194,304 sh (dead before x)
    unsigned short* t2pk  = t1pk + 4194304;                  // 4,194,304 sh -> ends at scr

    dim3 blk(256);

    // fused: zero padded bf16 conv inputs + prepack all conv + 1x1 weights
    setup_kernel<<<5832, blk, 0, stream>>>((uint4*)xt_r, 591872,
                                           df_b0_w, wp_b0, df_b1_w, wp_b1,
                                           br1_w, wp_br1, br2_w, wp_br2,
                                           t1_w, wp_t1, t2_w, wp_t2);
    // pack t1/t2 to A-frag bf16
    packX<<<16384, blk, 0, stream>>>(t1, t1pk);
    packX<<<16384, blk, 0, stream>>>(t2, t2pk);

    // res1/res2 = 1x1 conv(t1/t2) via MFMA GEMM
    gemm1x1_t<<<dim3(256, 4), blk, 0, stream>>>(t1pk, wp_t1, t1_b, res1);
    gemm1x1_t<<<dim3(256, 4), blk, 0, stream>>>(t2pk, wp_t2, t2_b, res2);
    sim_kernel<<<4096, blk, 0, stream>>>(res1, res2, simv);
    x_kernel2<<<dim3(128, 4), blk, 0, stream>>>(res1, res2, simv, xbuf);
    simp_kernel3<<<dim3(32, 4, 4), blk, 0, stream>>>(res1, res2, simv, attn_bf);
    // r = stdconv1x1(x) -> res1 (+ bf16 padded chunked copy)
    conv1x1_v2<<<dim3(8, 16, 4), blk, 0, stream>>>(xbuf, df_res_w, df_res_b, res1, 256, 128, 1, df_res_s, df_res_o, nullptr, xt_r);
    // b0 3x3 -> res2[0:64], b1 5x5 -> res2[64:128]
    convk_mfma<3, 64, 1, 4><<<dim3(256, 4), blk, 0, stream>>>(xt_r, wp_b0, df_b0_b, res2, 128, 0, 1, df_b0_s, df_b0_o, nullptr);
    convk_mfma<5, 64, 1, 4><<<dim3(256, 4), blk, 0, stream>>>(xt_r, wp_b1, df_b1_b, res2, 128, 64, 1, df_b1_s, df_b1_o, nullptr);
    // dif = stdconv1x1(b01) + r -> xbuf (+ bf16 padded chunked copy)
    conv1x1_v2<<<dim3(8, 16, 4), blk, 0, stream>>>(res2, df_fu_w, df_fu_b, xbuf, 128, 128, 1, df_fu_s, df_fu_o, res1, xt_dif);
    // inc1/inc2 (fp32 + bf16 B-frag-packed incT)
    convk_mfma<3, 128, 2, 4><<<dim3(256, 4), blk, 0, stream>>>(xt_dif, wp_br1, br1_b, res1, 128, 0, 0, nullptr, nullptr, incT1);
    convk_mfma<5, 128, 2, 4><<<dim3(256, 4), blk, 0, stream>>>(xt_dif, wp_br2, br2_b, res2, 128, 0, 0, nullptr, nullptr, incT2);
    // attention
    attnA_pass1<<<dim3(32, 8, 4), blk, 0, stream>>>(attn_bf, incT1, incT2, pmaxb, psumb);
    attnA_scale2<<<4096, blk, 0, stream>>>(attn_bf, pmaxb, psumb, mxb, attnS);
    attn_passB4<<<dim3(128, 8), blk, 0, stream>>>(attn_bf, attnS, incT1, incT2, mxb, res1, res2, abuf);
    // fused = stdconv1x1(concat(a1,a2)) + dif
    float* dif = xbuf;
    float* fused = xbuf + 2097152;
    conv1x1_v2<<<dim3(8, 16, 4), blk, 0, stream>>>(abuf, fu_w, fu_b, fused, 256, 128, 1, fu_s, fu_o, dif, nullptr);
    // bilinear 2x upsample -> d_out
    upsample_kernel<<<32768, blk, 0, stream>>>(fused, (float*)d_out);
}

// Round 9
// 460.624 us; speedup vs baseline: 1.1903x; 1.0747x over previous
//
#include <hip/hip_runtime.h>
#include <math.h>

#define HW 4096   // 64*64

typedef __attribute__((ext_vector_type(8))) short short8;
typedef __attribute__((ext_vector_type(4))) float floatx4;
typedef __attribute__((ext_vector_type(2))) float floatx2;

__device__ inline unsigned short f2bf(float f) {
    unsigned int u = __float_as_uint(f);
    unsigned int r = (u + 0x7fffu + ((u >> 16) & 1u)) >> 16;
    return (unsigned short)r;
}
__device__ inline float bf2f(unsigned short u) {
    return __uint_as_float(((unsigned int)u) << 16);
}

// Fragment-pack index helpers.
// A-frag pack of matrix M[R rows][K cols]: element (r,k) at
//   tile(r>>4, k>>5)*512 + ((k>>3)&3)*128 + (r&15)*8 + (k&7); wave loads base + tile*512 + lane*8.
// xt (conv activations) layout: [b][ci>>3][row(68)][col(68)][ci&7].

// ---------------- fused setup: zero padded xt + 6 weight prepacks
__device__ inline void prepack_dev(const float* __restrict__ w, unsigned short* __restrict__ wp,
                                   int CO, int CI, int KK, int i)
{
    if (i >= CO * CI * KK) return;
    int ci = i % CI;
    int t = i / CI;
    int co = t % CO;
    int kk = t / CO;
    int ti = (kk * (CO >> 4) + (co >> 4)) * (CI >> 5) + (ci >> 5);
    wp[(size_t)ti * 512 + ((ci >> 3) & 3) * 128 + (co & 15) * 8 + (ci & 7)]
        = f2bf(w[(co * CI + ci) * KK + kk]);
}

__global__ void setup_kernel(uint4* __restrict__ zp, int zn,
                             const float* __restrict__ w0, unsigned short* __restrict__ wp0,
                             const float* __restrict__ w1, unsigned short* __restrict__ wp1,
                             const float* __restrict__ w2, unsigned short* __restrict__ wp2,
                             const float* __restrict__ w3, unsigned short* __restrict__ wp3,
                             const float* __restrict__ w4, unsigned short* __restrict__ wp4,
                             const float* __restrict__ w5, unsigned short* __restrict__ wp5)
{
    int bx = blockIdx.x, tid = threadIdx.x;
    if (bx < 2312) {
        int i = bx * 256 + tid;
        if (i < zn) zp[i] = make_uint4(0u, 0u, 0u, 0u);
    } else if (bx < 2600) {
        prepack_dev(w0, wp0, 64, 128, 9,  (bx - 2312) * 256 + tid);
    } else if (bx < 3400) {
        prepack_dev(w1, wp1, 64, 128, 25, (bx - 2600) * 256 + tid);
    } else if (bx < 3976) {
        prepack_dev(w2, wp2, 128, 128, 9, (bx - 3400) * 256 + tid);
    } else if (bx < 5576) {
        prepack_dev(w3, wp3, 128, 128, 25,(bx - 3976) * 256 + tid);
    } else if (bx < 5704) {
        prepack_dev(w4, wp4, 128, 256, 1, (bx - 5576) * 256 + tid);
    } else {
        prepack_dev(w5, wp5, 128, 256, 1, (bx - 5704) * 256 + tid);
    }
}

// ---------------- late prepack: 1x1 weights needed after early buffers die
__global__ void prepack3(const float* __restrict__ w0, unsigned short* __restrict__ p0,
                         const float* __restrict__ w1, unsigned short* __restrict__ p1,
                         const float* __restrict__ w2, unsigned short* __restrict__ p2)
{
    int bx = blockIdx.x, tid = threadIdx.x;
    if (bx < 128)      prepack_dev(w0, p0, 128, 256, 1, bx * 256 + tid);
    else if (bx < 192) prepack_dev(w1, p1, 128, 128, 1, (bx - 128) * 256 + tid);
    else               prepack_dev(w2, p2, 128, 256, 1, (bx - 192) * 256 + tid);
}

// ---------------- pack fp32 [b][CI][4096px] -> A-frag-packed bf16 (px rows, ci k)
template<int CI32>
__global__ void packX(const float* __restrict__ in, unsigned short* __restrict__ out)
{
    int i = blockIdx.x * 256 + threadIdx.x;
    int b = i / (CI32 * 131072);
    int j = i % (CI32 * 131072);
    int ci = j >> 12, px = j & 4095;
    out[(size_t)b * (CI32 * 131072) + ((size_t)((px >> 4) * CI32 + (ci >> 5))) * 512
        + ((ci >> 3) & 3) * 128 + (px & 15) * 8 + (ci & 7)] = f2bf(in[i]);
}

// ---------------- 1x1 conv (CO=128) as bf16 MFMA GEMM: out = affine(W*X+b) [+addbuf] [+xt]
template<int KC>   // KC = CI/32
__global__ void __launch_bounds__(256)
gemm1x1(const unsigned short* __restrict__ Xpk, const unsigned short* __restrict__ Wpk,
        const float* __restrict__ bias, float* __restrict__ out,
        int do_affine, const float* __restrict__ s, const float* __restrict__ o,
        const float* __restrict__ addbuf, unsigned short* __restrict__ xt)
{
    int tid = threadIdx.x;
    int wv = tid >> 6, lane = tid & 63;
    int q = lane >> 4, n = lane & 15;
    int pxb = blockIdx.x;                       // 256 px-tiles of 16
    int b = blockIdx.y;
    int co0 = wv * 32;
    const unsigned short* apk = Xpk + (size_t)b * (KC * 131072) + (size_t)pxb * KC * 512 + lane * 8;
    const unsigned short* wpk = Wpk + (size_t)(co0 >> 4) * KC * 512 + lane * 8;
    floatx4 acc0 = (floatx4){0.f, 0.f, 0.f, 0.f};
    floatx4 acc1 = (floatx4){0.f, 0.f, 0.f, 0.f};
#pragma unroll
    for (int kc = 0; kc < KC; ++kc) {
        short8 a  = *(const short8*)(apk + kc * 512);
        short8 b0 = *(const short8*)(wpk + kc * 512);
        short8 b1 = *(const short8*)(wpk + (KC + kc) * 512);
        acc0 = __builtin_amdgcn_mfma_f32_16x16x32_bf16(a, b0, acc0, 0, 0, 0);
        acc1 = __builtin_amdgcn_mfma_f32_16x16x32_bf16(a, b1, acc1, 0, 0, 0);
    }
    int px0 = pxb * 16 + q * 4;
#pragma unroll
    for (int nt = 0; nt < 2; ++nt) {
        int co = co0 + nt * 16 + n;
        float bi = bias[co];
        float sc = do_affine ? s[co] : 1.f;
        float of = do_affine ? o[co] : 0.f;
        floatx4 v = nt ? acc1 : acc0;
        floatx4 res;
        if (addbuf) res = *(const floatx4*)(addbuf + ((size_t)(b * 128 + co)) * 4096 + px0);
#pragma unroll
        for (int r = 0; r < 4; ++r) {
            float val = v[r] + bi;
            if (do_affine) val = fmaxf(val, 0.f) * sc + of;
            if (addbuf) val += res[r];
            v[r] = val;
        }
        *(floatx4*)(out + ((size_t)(b * 128 + co)) * 4096 + px0) = v;
        if (xt) {
            unsigned short* xb = xt + ((size_t)(b * 16 + (co >> 3)) * 4624) * 8 + (co & 7);
#pragma unroll
            for (int r = 0; r < 4; ++r) {
                int px = px0 + r;
                int h = px >> 6, wc = px & 63;
                xb[(size_t)((h + 2) * 68 + (wc + 2)) * 8] = f2bf(v[r]);
            }
        }
    }
}

// ---------------- KxK conv as implicit-GEMM bf16 MFMA, m-split MS for occupancy
template<int K, int CO, int NB, int MS>
__global__ void __launch_bounds__(256)
convk_mfma(const unsigned short* __restrict__ xt, const unsigned short* __restrict__ wp,
           const float* __restrict__ bias, float* __restrict__ out,
           int OB, int co_off, int do_affine,
           const float* __restrict__ s, const float* __restrict__ o,
           unsigned short* __restrict__ incT)
{
    constexpr int CI = 128;
    constexpr int PAD = K / 2;
    constexpr int RO = 2 - PAD;
    constexpr int MT = 4 / MS;
    constexpr int CO16 = CO >> 4;
    constexpr int CI32 = CI >> 5;
    int tid = threadIdx.x;
    int wave = tid >> 6, lane = tid & 63;
    int h = blockIdx.x / MS, msb = blockIdx.x % MS;
    int b = blockIdx.y;
    int co0 = wave * 16 * NB;
    int n = lane & 15, q = lane >> 4;
    floatx4 acc[MT][NB];
#pragma unroll
    for (int mt = 0; mt < MT; ++mt)
#pragma unroll
        for (int nt = 0; nt < NB; ++nt) acc[mt][nt] = (floatx4){0.f, 0.f, 0.f, 0.f};

    const unsigned short* xb = xt + (size_t)(b * 16) * 4624 * 8;
    int mbase = msb * MT * 16;
    for (int ci0 = 0; ci0 < CI; ci0 += 32) {
#pragma unroll
        for (int kh = 0; kh < K; ++kh) {
            const unsigned short* xrow = xb + (size_t)(((ci0 >> 3) + q) * 4624 + (h + kh + RO) * 68 + RO) * 8;
            const unsigned short* wkh = wp + ((size_t)(kh * K) * CO16 * CI32 + (ci0 >> 5)) * 512 + lane * 8;
#pragma unroll
            for (int kw = 0; kw < K; ++kw) {
                short8 bfr[NB];
#pragma unroll
                for (int nt = 0; nt < NB; ++nt)
                    bfr[nt] = *(const short8*)(wkh + (size_t)((kw * CO16 + (co0 >> 4) + nt) * CI32) * 512);
#pragma unroll
                for (int mt = 0; mt < MT; ++mt) {
                    short8 afr = *(const short8*)(xrow + (mbase + mt * 16 + n + kw) * 8);
#pragma unroll
                    for (int nt = 0; nt < NB; ++nt)
                        acc[mt][nt] = __builtin_amdgcn_mfma_f32_16x16x32_bf16(afr, bfr[nt], acc[mt][nt], 0, 0, 0);
                }
            }
        }
    }
    int px0 = h * 64 + mbase + q * 4;
#pragma unroll
    for (int nt = 0; nt < NB; ++nt) {
        int co = co0 + nt * 16 + n;
        float bi = bias[co];
        float sc = do_affine ? s[co] : 1.f;
        float of = do_affine ? o[co] : 0.f;
        float* ob = out + ((size_t)(b * OB + co_off + co)) * HW;
        unsigned short* tb = incT ? incT + (size_t)b * 524288 : nullptr;
        int cpart = (co >> 5) * 512 + ((co >> 3) & 3) * 128 + (co & 7);
#pragma unroll
        for (int mt = 0; mt < MT; ++mt)
#pragma unroll
            for (int r = 0; r < 4; ++r) {
                int px = px0 + mt * 16 + r;
                float v = acc[mt][nt][r] + bi;
                if (do_affine) v = fmaxf(v, 0.f) * sc + of;
                ob[px] = v;
                if (incT) tb[(size_t)((px >> 4) * 2048 + cpart + (px & 15) * 8)] = f2bf(v);
            }
    }
}

// ---------------- cosine similarity over groups of 128 consecutive floats
__global__ void sim_kernel(const float* __restrict__ r1, const float* __restrict__ r2,
                           float* __restrict__ sim)
{
    int gw = blockIdx.x * 4 + (threadIdx.x >> 6);
    int lane = threadIdx.x & 63;
    int b = gw >> 12, n = gw & 4095;
    const float* p1 = r1 + (size_t)b * 524288 + (size_t)n * 128;
    const float* p2 = r2 + (size_t)b * 524288 + (size_t)n * 128;
    float a0 = p1[lane], a1 = p1[lane + 64];
    float b0 = p2[lane], b1 = p2[lane + 64];
    float dot = a0 * b0 + a1 * b1;
    float n1 = a0 * a0 + a1 * a1;
    float n2 = b0 * b0 + b1 * b1;
    for (int m = 32; m; m >>= 1) {
        dot += __shfl_xor(dot, m);
        n1  += __shfl_xor(n1, m);
        n2  += __shfl_xor(n2, m);
    }
    if (lane == 0) sim[b * 4096 + n] = dot / fmaxf(sqrtf(n1) * sqrtf(n2), 1e-8f);
}

// ---------------- x = concat(dif1, dif2): LDS-transposed, coalesced
__global__ void __launch_bounds__(256)
x_kernel2(const float* __restrict__ r1, const float* __restrict__ r2,
          const float* __restrict__ sim, float* __restrict__ xo)
{
    __shared__ float ls1[32 * 129], ls2[32 * 129];
    int b = blockIdx.y, p0 = blockIdx.x * 32, tid = threadIdx.x;
    const float* F1 = r1 + (size_t)b * 524288;
    const float* F2 = r2 + (size_t)b * 524288;
    for (int i = tid; i < 32 * 128; i += 256) {
        int p = i >> 7, c = i & 127;
        ls1[p * 129 + c] = F1[p0 * 128 + i];
        ls2[p * 129 + c] = F2[p0 * 128 + i];
    }
    __syncthreads();
    for (int j = tid; j < 256 * 32; j += 256) {
        int p = j & 31, cc = j >> 5;
        int c = cc & 127;
        float sv = sim[b * 4096 + p0 + p];
        const float* F = (cc & 128) ? F2 : F1;
        float t1v = ((cc & 128) ? ls2 : ls1)[p * 129 + c];
        xo[(size_t)b * 1048576 + (size_t)cc * 4096 + p0 + p] = t1v * (1.f - sv) + F[(size_t)c * 4096 + p0 + p];
    }
}

// ---------------- attn = avgpool2(|sim1-sim2|) -> A-frag-packed bf16, channel-split
__global__ void __launch_bounds__(256)
simp_kernel3(const float* __restrict__ r1, const float* __restrict__ r2,
             const float* __restrict__ sim, unsigned short* __restrict__ attn_pk)
{
    __shared__ float lsd[64 * 33];
    int b = blockIdx.y, h2 = blockIdx.x, cg = blockIdx.z, tid = threadIdx.x;
    const float* F1 = r1 + (size_t)b * 524288;
    const float* F2 = r2 + (size_t)b * 524288;
    const float* sb = sim + b * 4096;
    int w2 = tid & 31, cl = tid >> 5;
    float acc[4] = {};
    for (int dh = 0; dh < 2; ++dh) {
        int prow = h2 * 128 + dh * 64;
        __syncthreads();
        for (int i = tid; i < 64 * 32; i += 256) {
            int p = i >> 5, c = i & 31;
            size_t gi = (size_t)(prow + p) * 128 + cg * 32 + c;
            lsd[p * 33 + c] = F1[gi] - F2[gi];
        }
        __syncthreads();
#pragma unroll
        for (int k = 0; k < 4; ++k) {
            int c = cl + 8 * k;
            int cG = cg * 32 + c;
#pragma unroll
            for (int dw = 0; dw < 2; ++dw) {
                int pl = 2 * w2 + dw;
                int p = prow + pl;
                float d = lsd[pl * 33 + c] * sb[p]
                        + (F1[(size_t)cG * 4096 + p] - F2[(size_t)cG * 4096 + p]);
                acc[k] += fabsf(d);
            }
        }
    }
#pragma unroll
    for (int k = 0; k < 4; ++k) {
        int cG = cg * 32 + cl + 8 * k;
        int f = cG * 1024 + h2 * 32 + w2;
        int n = f >> 7, c = f & 127;
        attn_pk[(size_t)b * 131072 + ((n >> 4) * 4 + (c >> 5)) * 512
                + ((c >> 3) & 3) * 128 + (n & 15) * 8 + (c & 7)] = f2bf(acc[k] * 0.25f);
    }
}

// ---------------- attention pass1: 2 n-tiles/block, fused online (max,sum), z-split
__global__ void __launch_bounds__(256)
attnA_pass1(const unsigned short* __restrict__ attn_pk,
            const unsigned short* __restrict__ incT1, const unsigned short* __restrict__ incT2,
            float* __restrict__ pmax, float* __restrict__ psum)
{
    __shared__ float lm[4][32], ls[4][32];
    int pair = blockIdx.y;
    int b = pair & 3, br = pair >> 2;
    int z = blockIdx.z;
    int tid = threadIdx.x;
    int wave = tid >> 6, lane = tid & 63;
    int n0 = blockIdx.x * 32;
    int q = lane >> 4;
    int col = lane & 15;
    const unsigned short* apk = attn_pk + (size_t)b * 131072 + (size_t)blockIdx.x * 4096 + lane * 8;
    short8 afrA[4], afrB[4];
#pragma unroll
    for (int kc = 0; kc < 4; ++kc) {
        afrA[kc] = *(const short8*)(apk + kc * 512);
        afrB[kc] = *(const short8*)(apk + 2048 + kc * 512);
    }
    const unsigned short* ibp = (br ? incT2 : incT1) + (size_t)b * 524288 + lane * 8;
    short8 bbuf[2][4];
    {
        const unsigned short* brow = ibp + (size_t)(z * 64 + wave * 16) * 2048;
#pragma unroll
        for (int kc = 0; kc < 4; ++kc) bbuf[0][kc] = *(const short8*)(brow + kc * 512);
        brow += 2048;
#pragma unroll
        for (int kc = 0; kc < 4; ++kc) bbuf[1][kc] = *(const short8*)(brow + kc * 512);
    }
    float rmA[4], rsA[4], rmB[4], rsB[4];
#pragma unroll
    for (int r = 0; r < 4; ++r) { rmA[r] = -3.0e38f; rsA[r] = 0.f; rmB[r] = -3.0e38f; rsB[r] = 0.f; }
#pragma unroll
    for (int mt = 0; mt < 16; ++mt) {
        const int cur = mt & 1;
        floatx4 accA = (floatx4){0.f, 0.f, 0.f, 0.f};
        floatx4 accB = (floatx4){0.f, 0.f, 0.f, 0.f};
#pragma unroll
        for (int kc = 0; kc < 4; ++kc) {
            accA = __builtin_amdgcn_mfma_f32_16x16x32_bf16(afrA[kc], bbuf[cur][kc], accA, 0, 0, 0);
            accB = __builtin_amdgcn_mfma_f32_16x16x32_bf16(afrB[kc], bbuf[cur][kc], accB, 0, 0, 0);
        }
        if (mt < 14) {
            const unsigned short* brow = ibp + (size_t)(z * 64 + wave * 16 + mt + 2) * 2048;
#pragma unroll
            for (int kc = 0; kc < 4; ++kc) bbuf[cur][kc] = *(const short8*)(brow + kc * 512);
        }
#pragma unroll
        for (int r = 0; r < 4; ++r) {
            float vA = accA[r];
            float nmA = fmaxf(rmA[r], vA);
            rsA[r] = rsA[r] * __expf(rmA[r] - nmA) + __expf(vA - nmA);
            rmA[r] = nmA;
            float vB = accB[r];
            float nmB = fmaxf(rmB[r], vB);
            rsB[r] = rsB[r] * __expf(rmB[r] - nmB) + __expf(vB - nmB);
            rmB[r] = nmB;
        }
    }
#pragma unroll
    for (int d = 1; d < 16; d <<= 1) {
#pragma unroll
        for (int r = 0; r < 4; ++r) {
            float om = __shfl_xor(rmA[r], d);
            float os = __shfl_xor(rsA[r], d);
            float nm = fmaxf(rmA[r], om);
            rsA[r] = rsA[r] * __expf(rmA[r] - nm) + os * __expf(om - nm);
            rmA[r] = nm;
            om = __shfl_xor(rmB[r], d);
            os = __shfl_xor(rsB[r], d);
            nm = fmaxf(rmB[r], om);
            rsB[r] = rsB[r] * __expf(rmB[r] - nm) + os * __expf(om - nm);
            rmB[r] = nm;
        }
    }
    if (col == 0) {
#pragma unroll
        for (int r = 0; r < 4; ++r) {
            lm[wave][q * 4 + r] = rmA[r];      ls[wave][q * 4 + r] = rsA[r];
            lm[wave][16 + q * 4 + r] = rmB[r]; ls[wave][16 + q * 4 + r] = rsB[r];
        }
    }
    __syncthreads();
    if (tid < 32) {
        float bm = lm[0][tid], bs = ls[0][tid];
        for (int w = 1; w < 4; ++w) {
            float om = lm[w][tid], os = ls[w][tid];
            float nm = fmaxf(bm, om);
            bs = bs * __expf(bm - nm) + os * __expf(om - nm);
            bm = nm;
        }
        pmax[((size_t)pair * 4 + z) * 1024 + n0 + tid] = bm;
        psum[((size_t)pair * 4 + z) * 1024 + n0 + tid] = bs;
    }
}

// ---------------- fused: merge z partials (per thread) + scale attn -> attnS_pk; write mx
__global__ void attnA_scale2(const unsigned short* __restrict__ attn_pk,
                             const float* __restrict__ pmax, const float* __restrict__ psum,
                             float* __restrict__ mx, unsigned short* __restrict__ attnS_pk)
{
    int i = blockIdx.x * 256 + threadIdx.x;   // 1,048,576 (coalesced over packed output)
    int pair = i >> 17;
    int o = i & 131071;
    int j = o & 7, lane = (o >> 3) & 63, ct = (o >> 9) & 7, kcn = o >> 12;
    int c = ct * 16 + (lane & 15);
    int n = kcn * 32 + (lane >> 4) * 8 + j;
    int b = pair & 3;
    float bm = pmax[((size_t)pair * 4) * 1024 + n];
    float bs = psum[((size_t)pair * 4) * 1024 + n];
#pragma unroll
    for (int z = 1; z < 4; ++z) {
        float om = pmax[((size_t)pair * 4 + z) * 1024 + n];
        float os = psum[((size_t)pair * 4 + z) * 1024 + n];
        float nm = fmaxf(bm, om);
        bs = bs * __expf(bm - nm) + os * __expf(om - nm);
        bm = nm;
    }
    if (c == 0) mx[pair * 1024 + n] = bm;
    float rc = 1.f / bs;
    int ii = b * 131072 + ((n >> 4) * 4 + (c >> 5)) * 512
           + ((c >> 3) & 3) * 128 + (n & 15) * 8 + (c & 7);
    attnS_pk[(size_t)i] = f2bf(bf2f(attn_pk[ii]) * rc);
}

// ---------------- attention pass B: deep software pipeline, LDS-combined epilogue
// (R6-harness-verified passB4, verbatim)
__global__ void __launch_bounds__(256)
attn_passB4(const unsigned short* __restrict__ attn_pk,
            const unsigned short* __restrict__ attnS_pk,
            const unsigned short* __restrict__ incT1, const unsigned short* __restrict__ incT2,
            const float* __restrict__ mx,
            const float* __restrict__ inc1, const float* __restrict__ inc2,
            float* __restrict__ abuf)
{
    __shared__ unsigned short lp[4][16 * 36];
    __shared__ float lred[2][2048];
    int pair = blockIdx.y;
    int b = pair & 3, br = pair >> 2;
    int tid = threadIdx.x;
    int wv = tid >> 6, lane = tid & 63;
    int q = lane >> 4, col = lane & 15;
    int msub = wv & 1, nh = wv >> 1;
    int m0 = blockIdx.x * 32 + msub * 16;
    int mtg = m0 >> 4;
    const unsigned short* ibp = (br ? incT2 : incT1) + (size_t)b * 524288 + lane * 8;
    short8 bfrS[4];
#pragma unroll
    for (int kc = 0; kc < 4; ++kc)
        bfrS[kc] = *(const short8*)(ibp + (size_t)(mtg * 4 + kc) * 512);
    const float* mxp = mx + pair * 1024 + nh * 512;
    const unsigned short* aspk = attnS_pk + (size_t)pair * 131072 + lane * 8;
    const unsigned short* apk = attn_pk + (size_t)b * 131072 + lane * 8;
    floatx4 oacc[8];
#pragma unroll
    for (int ct = 0; ct < 8; ++ct) oacc[ct] = (floatx4){0.f, 0.f, 0.f, 0.f};
    unsigned short* lw = lp[wv];

    short8 arP[2][2][4];
    short8 asP[2][8];
    floatx4 mxq[2][2];
    floatx4 sacc[2][2];

#pragma unroll
    for (int t = 0; t < 2; ++t)
#pragma unroll
        for (int kc = 0; kc < 4; ++kc)
            arP[0][t][kc] = *(const short8*)(apk + (size_t)(((nh * 32 + t) * 4 + kc)) * 512);
#pragma unroll
    for (int ct = 0; ct < 8; ++ct)
        asP[0][ct] = *(const short8*)(aspk + (size_t)((nh * 16) * 8 + ct) * 512);
#pragma unroll
    for (int t = 0; t < 2; ++t)
        mxq[0][t] = *(const floatx4*)(mxp + t * 16 + q * 4);
#pragma unroll
    for (int t = 0; t < 2; ++t) {
        floatx4 a = (floatx4){0.f, 0.f, 0.f, 0.f};
#pragma unroll
        for (int kc = 0; kc < 4; ++kc)
            a = __builtin_amdgcn_mfma_f32_16x16x32_bf16(arP[0][t][kc], bfrS[kc], a, 0, 0, 0);
        sacc[0][t] = a;
    }
#pragma unroll
    for (int t = 0; t < 2; ++t)
#pragma unroll
        for (int kc = 0; kc < 4; ++kc)
            arP[1][t][kc] = *(const short8*)(apk + (size_t)(((nh * 32 + 2 + t) * 4 + kc)) * 512);

#pragma unroll
    for (int nc = 0; nc < 16; ++nc) {
        const int cur = nc & 1, nxt = cur ^ 1;
#pragma unroll
        for (int t = 0; t < 2; ++t) {
            floatx4 sv = sacc[cur][t];
            floatx4 mv = mxq[cur][t];
            unsigned int p01 = (unsigned int)f2bf(__expf(sv[0] - mv[0]))
                             | ((unsigned int)f2bf(__expf(sv[1] - mv[1])) << 16);
            unsigned int p23 = (unsigned int)f2bf(__expf(sv[2] - mv[2]))
                             | ((unsigned int)f2bf(__expf(sv[3] - mv[3])) << 16);
            *(uint2*)&lw[col * 36 + t * 16 + q * 4] = make_uint2(p01, p23);
        }
        if (nc < 15) {
#pragma unroll
            for (int ct = 0; ct < 8; ++ct)
                asP[nxt][ct] = *(const short8*)(aspk + (size_t)(((nh * 16 + nc + 1) * 8 + ct)) * 512);
#pragma unroll
            for (int t = 0; t < 2; ++t)
                mxq[nxt][t] = *(const floatx4*)(mxp + (nc + 1) * 32 + t * 16 + q * 4);
        }
        short8 pb = *(const short8*)&lw[col * 36 + q * 8];
        if (nc < 15) {
#pragma unroll
            for (int t = 0; t < 2; ++t) {
                floatx4 a = (floatx4){0.f, 0.f, 0.f, 0.f};
#pragma unroll
                for (int kc = 0; kc < 4; ++kc)
                    a = __builtin_amdgcn_mfma_f32_16x16x32_bf16(arP[nxt][t][kc], bfrS[kc], a, 0, 0, 0);
                sacc[nxt][t] = a;
            }
        }
        if (nc < 14) {
#pragma unroll
            for (int t = 0; t < 2; ++t)
#pragma unroll
                for (int kc = 0; kc < 4; ++kc)
                    arP[cur][t][kc] = *(const short8*)(apk + (size_t)(((nh * 32 + (nc + 2) * 2 + t) * 4 + kc)) * 512);
        }
#pragma unroll
        for (int ct = 0; ct < 8; ++ct)
            oacc[ct] = __builtin_amdgcn_mfma_f32_16x16x32_bf16(asP[cur][ct], pb, oacc[ct], 0, 0, 0);
    }

    if (nh == 1) {
        float* lr = lred[msub];
#pragma unroll
        for (int ct = 0; ct < 8; ++ct)
#pragma unroll
            for (int r = 0; r < 4; ++r)
                lr[(ct * 16 + q * 4 + r) * 16 + col] = oacc[ct][r];
    }
    __syncthreads();
    if (nh == 0) {
        const float* lr = lred[msub];
        const float* resid = (br ? inc2 : inc1) + (size_t)b * 524288;
        float* op = abuf + ((size_t)(b * 256 + br * 128)) * 4096;
        int m = m0 + col;
#pragma unroll
        for (int ct = 0; ct < 8; ++ct)
#pragma unroll
            for (int r = 0; r < 4; ++r) {
                int row = ct * 16 + q * 4 + r;
                op[(size_t)row * 4096 + m] = oacc[ct][r] + lr[row * 16 + col]
                                           + resid[(size_t)row * 4096 + m];
            }
    }
}

// ---------------- bilinear 2x upsample, half-pixel centers, edge clamp
__global__ void upsample_kernel(const float* __restrict__ in, float* __restrict__ out)
{
    int i = blockIdx.x * 256 + threadIdx.x;
    int x = i & 127, y = (i >> 7) & 127, bc = i >> 14;
    const float* ib = in + (size_t)bc * HW;
    float sy = 0.5f * y - 0.25f;
    float sx = 0.5f * x - 0.25f;
    int y0 = (int)floorf(sy); float ty = sy - y0;
    int x0 = (int)floorf(sx); float tx = sx - x0;
    int y0c = min(max(y0, 0), 63), y1c = min(max(y0 + 1, 0), 63);
    int x0c = min(max(x0, 0), 63), x1c = min(max(x0 + 1, 0), 63);
    float v00 = ib[y0c * 64 + x0c], v01 = ib[y0c * 64 + x1c];
    float v10 = ib[y1c * 64 + x0c], v11 = ib[y1c * 64 + x1c];
    out[i] = (1.f - ty) * ((1.f - tx) * v00 + tx * v01) + ty * ((1.f - tx) * v10 + tx * v11);
}

extern "C" void kernel_launch(void* const* d_in, const int* in_sizes, int n_in,
                              void* d_out, int out_size, void* d_ws, size_t ws_size,
                              hipStream_t stream)
{
    const float* t1       = (const float*)d_in[0];
    const float* t2       = (const float*)d_in[1];
    const float* t1_w     = (const float*)d_in[2];
    const float* t1_b     = (const float*)d_in[3];
    const float* t2_w     = (const float*)d_in[4];
    const float* t2_b     = (const float*)d_in[5];
    const float* df_res_w = (const float*)d_in[6];
    const float* df_res_b = (const float*)d_in[7];
    const float* df_res_s = (const float*)d_in[8];
    const float* df_res_o = (const float*)d_in[9];
    const float* df_b0_w  = (const float*)d_in[10];
    const float* df_b0_b  = (const float*)d_in[11];
    const float* df_b0_s  = (const float*)d_in[12];
    const float* df_b0_o  = (const float*)d_in[13];
    const float* df_b1_w  = (const float*)d_in[14];
    const float* df_b1_b  = (const float*)d_in[15];
    const float* df_b1_s  = (const float*)d_in[16];
    const float* df_b1_o  = (const float*)d_in[17];
    const float* df_fu_w  = (const float*)d_in[18];
    const float* df_fu_b  = (const float*)d_in[19];
    const float* df_fu_s  = (const float*)d_in[20];
    const float* df_fu_o  = (const float*)d_in[21];
    const float* br1_w    = (const float*)d_in[22];
    const float* br1_b    = (const float*)d_in[23];
    const float* br2_w    = (const float*)d_in[24];
    const float* br2_b    = (const float*)d_in[25];
    const float* fu_w     = (const float*)d_in[26];
    const float* fu_b     = (const float*)d_in[27];
    const float* fu_s     = (const float*)d_in[28];
    const float* fu_o     = (const float*)d_in[29];

    float* ws = (float*)d_ws;
    float* res1 = ws;                   // 2,097,152 f  (res1 -> r -> inc1 fp32)
    float* res2 = ws + 2097152;         // 2,097,152 f  (res2 -> b01 -> inc2 fp32)
    float* xbuf = ws + 4194304;         // 4,194,304 f  (t1pk/t2pk early; x -> dif; fused at +2M)
    float* scr  = ws + 8388608;         // 4,194,304 f  bf16/f32 scratch region
    float* abuf = ws + 12582912;        // 4,194,304 f  (xpk/b01pk early; concat(a1,a2) late)
    float* attnS_f = ws + 16777216;     // 524,288 f -> wp_t1/t2/res/fu1 early; attnS bf16 (packed)
    float* simv = ws + 17301504;        // 16,384 f (sim early; wp_fu2 late)
    float* mxb  = ws + 17317888;        // 8,192 f

    unsigned short* us     = (unsigned short*)scr;
    unsigned short* wp_b0  = us;                 // 73,728
    unsigned short* wp_b1  = us + 73728;         // 204,800
    unsigned short* wp_br1 = us + 278528;        // 147,456
    unsigned short* wp_br2 = us + 425984;        // 409,600 -> ends 835,584
    unsigned short* xt_r   = us + 851968;        // 2,367,488 -> ends 3,219,456
    unsigned short* xt_dif = us + 3219456;       // 2,367,488 -> ends 5,586,944
    unsigned short* incT1  = us + 5586944;       // 2,097,152 -> ends 7,684,096
    unsigned short* incT2  = us + 851968;        // 2,097,152 (overlays dead xt_r)
    unsigned short* attn_bf= us + 7684096;       // 524,288 -> ends 8,208,384 (f 4,104,192)
    float* scrF = scr;
    float* pmaxb = scrF + 4104192;      // 32,768 f
    float* psumb = scrF + 4136960;      // 32,768 f
    unsigned short* attnS  = (unsigned short*)attnS_f;
    // early-phase overlays (dead before their regions' later use)
    unsigned short* wp_t1  = (unsigned short*)attnS_f;       // 32,768 sh (dead before attnS)
    unsigned short* wp_t2  = wp_t1 + 32768;                  // 32,768 sh
    unsigned short* wp_res = wp_t1 + 65536;                  // 32,768 sh (dead before attnS)
    unsigned short* wp_fu1 = wp_t1 + 98304;                  // 16,384 sh (dead before attnS)
    unsigned short* wp_fu2 = (unsigned short*)simv;          // 32,768 sh (written after simv dead)
    unsigned short* t1pk   = (unsigned short*)xbuf;          // 4,194,304 sh (dead before x)
    unsigned short* t2pk   = t1pk + 4194304;                 // 4,194,304 sh -> ends at scr
    unsigned short* xpk    = (unsigned short*)abuf;          // 4,194,304 sh (dead before abuf write)
    unsigned short* b01pk  = (unsigned short*)abuf;          // 2,097,152 sh (reuse; xpk dead first)
    unsigned short* abufpk = us;                             // 4,194,304 sh (scr all dead post-attn)

    dim3 blk(256);

    // fused: zero padded bf16 conv inputs + prepack all conv + t1/t2 1x1 weights
    setup_kernel<<<5832, blk, 0, stream>>>((uint4*)xt_r, 591872,
                                           df_b0_w, wp_b0, df_b1_w, wp_b1,
                                           br1_w, wp_br1, br2_w, wp_br2,
                                           t1_w, wp_t1, t2_w, wp_t2);
    // pack t1/t2 to A-frag bf16
    packX<8><<<16384, blk, 0, stream>>>(t1, t1pk);
    packX<8><<<16384, blk, 0, stream>>>(t2, t2pk);

    // res1/res2 = 1x1 conv(t1/t2) via MFMA GEMM
    gemm1x1<8><<<dim3(256, 4), blk, 0, stream>>>(t1pk, wp_t1, t1_b, res1, 0, nullptr, nullptr, nullptr, nullptr);
    gemm1x1<8><<<dim3(256, 4), blk, 0, stream>>>(t2pk, wp_t2, t2_b, res2, 0, nullptr, nullptr, nullptr, nullptr);
    sim_kernel<<<4096, blk, 0, stream>>>(res1, res2, simv);
    x_kernel2<<<dim3(128, 4), blk, 0, stream>>>(res1, res2, simv, xbuf);
    simp_kernel3<<<dim3(32, 4, 4), blk, 0, stream>>>(res1, res2, simv, attn_bf);
    // late weight prepack (simv now dead; attnS region still free)
    prepack3<<<320, blk, 0, stream>>>(df_res_w, wp_res, df_fu_w, wp_fu1, fu_w, wp_fu2);
    // r = stdconv1x1(x) via MFMA GEMM (+ bf16 padded chunked copy)
    packX<8><<<16384, blk, 0, stream>>>(xbuf, xpk);
    gemm1x1<8><<<dim3(256, 4), blk, 0, stream>>>(xpk, wp_res, df_res_b, res1, 1, df_res_s, df_res_o, nullptr, xt_r);
    // b0 3x3 -> res2[0:64], b1 5x5 -> res2[64:128]
    convk_mfma<3, 64, 1, 4><<<dim3(256, 4), blk, 0, stream>>>(xt_r, wp_b0, df_b0_b, res2, 128, 0, 1, df_b0_s, df_b0_o, nullptr);
    convk_mfma<5, 64, 1, 4><<<dim3(256, 4), blk, 0, stream>>>(xt_r, wp_b1, df_b1_b, res2, 128, 64, 1, df_b1_s, df_b1_o, nullptr);
    // dif = stdconv1x1(b01) + r via MFMA GEMM (+ bf16 padded chunked copy)
    packX<4><<<8192, blk, 0, stream>>>(res2, b01pk);
    gemm1x1<4><<<dim3(256, 4), blk, 0, stream>>>(b01pk, wp_fu1, df_fu_b, xbuf, 1, df_fu_s, df_fu_o, res1, xt_dif);
    // inc1/inc2 (fp32 + bf16 B-frag-packed incT)
    convk_mfma<3, 128, 2, 4><<<dim3(256, 4), blk, 0, stream>>>(xt_dif, wp_br1, br1_b, res1, 128, 0, 0, nullptr, nullptr, incT1);
    convk_mfma<5, 128, 2, 4><<<dim3(256, 4), blk, 0, stream>>>(xt_dif, wp_br2, br2_b, res2, 128, 0, 0, nullptr, nullptr, incT2);
    // attention
    attnA_pass1<<<dim3(32, 8, 4), blk, 0, stream>>>(attn_bf, incT1, incT2, pmaxb, psumb);
    attnA_scale2<<<4096, blk, 0, stream>>>(attn_bf, pmaxb, psumb, mxb, attnS);
    attn_passB4<<<dim3(128, 8), blk, 0, stream>>>(attn_bf, attnS, incT1, incT2, mxb, res1, res2, abuf);
    // fused = stdconv1x1(concat(a1,a2)) + dif via MFMA GEMM
    float* dif = xbuf;
    float* fused = xbuf + 2097152;
    packX<8><<<16384, blk, 0, stream>>>(abuf, abufpk);
    gemm1x1<8><<<dim3(256, 4), blk, 0, stream>>>(abufpk, wp_fu2, fu_b, fused, 1, fu_s, fu_o, dif, nullptr);
    // bilinear 2x upsample -> d_out
    upsample_kernel<<<32768, blk, 0, stream>>>(fused, (float*)d_out);
}

// Round 12
// 453.045 us; speedup vs baseline: 1.2102x; 1.0167x over previous
//
#include <hip/hip_runtime.h>
#include <math.h>

#define HW 4096   // 64*64

typedef __attribute__((ext_vector_type(8))) short short8;
typedef __attribute__((ext_vector_type(4))) float floatx4;
typedef __attribute__((ext_vector_type(2))) float floatx2;

__device__ inline unsigned short f2bf(float f) {
    unsigned int u = __float_as_uint(f);
    unsigned int r = (u + 0x7fffu + ((u >> 16) & 1u)) >> 16;
    return (unsigned short)r;
}
__device__ inline float bf2f(unsigned short u) {
    return __uint_as_float(((unsigned int)u) << 16);
}

// Fragment-pack index helpers.
// A-frag pack of matrix M[R rows][K cols]: element (r,k) at
//   tile(r>>4, k>>5)*512 + ((k>>3)&3)*128 + (r&15)*8 + (k&7); wave loads base + tile*512 + lane*8.
// xt (conv activations) layout: [b][ci>>3][row(68)][col(68)][ci&7].

// ---------------- fused setup: zero padded xt + 6 weight prepacks
__device__ inline void prepack_dev(const float* __restrict__ w, unsigned short* __restrict__ wp,
                                   int CO, int CI, int KK, int i)
{
    if (i >= CO * CI * KK) return;
    int ci = i % CI;
    int t = i / CI;
    int co = t % CO;
    int kk = t / CO;
    int ti = (kk * (CO >> 4) + (co >> 4)) * (CI >> 5) + (ci >> 5);
    wp[(size_t)ti * 512 + ((ci >> 3) & 3) * 128 + (co & 15) * 8 + (ci & 7)]
        = f2bf(w[(co * CI + ci) * KK + kk]);
}

__global__ void setup_kernel(uint4* __restrict__ zp, int zn,
                             const float* __restrict__ w0, unsigned short* __restrict__ wp0,
                             const float* __restrict__ w1, unsigned short* __restrict__ wp1,
                             const float* __restrict__ w2, unsigned short* __restrict__ wp2,
                             const float* __restrict__ w3, unsigned short* __restrict__ wp3,
                             const float* __restrict__ w4, unsigned short* __restrict__ wp4,
                             const float* __restrict__ w5, unsigned short* __restrict__ wp5)
{
    int bx = blockIdx.x, tid = threadIdx.x;
    if (bx < 2312) {
        int i = bx * 256 + tid;
        if (i < zn) zp[i] = make_uint4(0u, 0u, 0u, 0u);
    } else if (bx < 2600) {
        prepack_dev(w0, wp0, 64, 128, 9,  (bx - 2312) * 256 + tid);
    } else if (bx < 3400) {
        prepack_dev(w1, wp1, 64, 128, 25, (bx - 2600) * 256 + tid);
    } else if (bx < 3976) {
        prepack_dev(w2, wp2, 128, 128, 9, (bx - 3400) * 256 + tid);
    } else if (bx < 5576) {
        prepack_dev(w3, wp3, 128, 128, 25,(bx - 3976) * 256 + tid);
    } else if (bx < 5704) {
        prepack_dev(w4, wp4, 128, 256, 1, (bx - 5576) * 256 + tid);
    } else {
        prepack_dev(w5, wp5, 128, 256, 1, (bx - 5704) * 256 + tid);
    }
}

// ---------------- late prepack: 1x1 weights needed after early buffers die
__global__ void prepack3(const float* __restrict__ w0, unsigned short* __restrict__ p0,
                         const float* __restrict__ w1, unsigned short* __restrict__ p1,
                         const float* __restrict__ w2, unsigned short* __restrict__ p2)
{
    int bx = blockIdx.x, tid = threadIdx.x;
    if (bx < 128)      prepack_dev(w0, p0, 128, 256, 1, bx * 256 + tid);
    else if (bx < 192) prepack_dev(w1, p1, 128, 128, 1, (bx - 128) * 256 + tid);
    else               prepack_dev(w2, p2, 128, 256, 1, (bx - 192) * 256 + tid);
}

// ---------------- pack fp32 [b][CI][4096px] -> A-frag-packed bf16 (px rows, ci k)
template<int CI32>
__global__ void packX(const float* __restrict__ in, unsigned short* __restrict__ out)
{
    int i = blockIdx.x * 256 + threadIdx.x;
    int b = i / (CI32 * 131072);
    int j = i % (CI32 * 131072);
    int ci = j >> 12, px = j & 4095;
    out[(size_t)b * (CI32 * 131072) + ((size_t)((px >> 4) * CI32 + (ci >> 5))) * 512
        + ((ci >> 3) & 3) * 128 + (px & 15) * 8 + (ci & 7)] = f2bf(in[i]);
}

// ---------------- 1x1 conv (CO=128) as bf16 MFMA GEMM: out = affine(W*X+b) [+addbuf] [+xt]
template<int KC>   // KC = CI/32
__global__ void __launch_bounds__(256)
gemm1x1(const unsigned short* __restrict__ Xpk, const unsigned short* __restrict__ Wpk,
        const float* __restrict__ bias, float* __restrict__ out,
        int do_affine, const float* __restrict__ s, const float* __restrict__ o,
        const float* __restrict__ addbuf, unsigned short* __restrict__ xt)
{
    int tid = threadIdx.x;
    int wv = tid >> 6, lane = tid & 63;
    int q = lane >> 4, n = lane & 15;
    int pxb = blockIdx.x;                       // 256 px-tiles of 16
    int b = blockIdx.y;
    int co0 = wv * 32;
    const unsigned short* apk = Xpk + (size_t)b * (KC * 131072) + (size_t)pxb * KC * 512 + lane * 8;
    const unsigned short* wpk = Wpk + (size_t)(co0 >> 4) * KC * 512 + lane * 8;
    floatx4 acc0 = (floatx4){0.f, 0.f, 0.f, 0.f};
    floatx4 acc1 = (floatx4){0.f, 0.f, 0.f, 0.f};
#pragma unroll
    for (int kc = 0; kc < KC; ++kc) {
        short8 a  = *(const short8*)(apk + kc * 512);
        short8 b0 = *(const short8*)(wpk + kc * 512);
        short8 b1 = *(const short8*)(wpk + (KC + kc) * 512);
        acc0 = __builtin_amdgcn_mfma_f32_16x16x32_bf16(a, b0, acc0, 0, 0, 0);
        acc1 = __builtin_amdgcn_mfma_f32_16x16x32_bf16(a, b1, acc1, 0, 0, 0);
    }
    int px0 = pxb * 16 + q * 4;
#pragma unroll
    for (int nt = 0; nt < 2; ++nt) {
        int co = co0 + nt * 16 + n;
        float bi = bias[co];
        float sc = do_affine ? s[co] : 1.f;
        float of = do_affine ? o[co] : 0.f;
        floatx4 v = nt ? acc1 : acc0;
        floatx4 res;
        if (addbuf) res = *(const floatx4*)(addbuf + ((size_t)(b * 128 + co)) * 4096 + px0);
#pragma unroll
        for (int r = 0; r < 4; ++r) {
            float val = v[r] + bi;
            if (do_affine) val = fmaxf(val, 0.f) * sc + of;
            if (addbuf) val += res[r];
            v[r] = val;
        }
        *(floatx4*)(out + ((size_t)(b * 128 + co)) * 4096 + px0) = v;
        if (xt) {
            unsigned short* xb = xt + ((size_t)(b * 16 + (co >> 3)) * 4624) * 8 + (co & 7);
#pragma unroll
            for (int r = 0; r < 4; ++r) {
                int px = px0 + r;
                int h = px >> 6, wc = px & 63;
                xb[(size_t)((h + 2) * 68 + (wc + 2)) * 8] = f2bf(v[r]);
            }
        }
    }
}

// ---------------- KxK conv as implicit-GEMM bf16 MFMA, m-split MS for occupancy
// (R9-verified: incT B-frag pack with hardcoded 2048, local-co cpart)
template<int K, int CO, int NB, int MS>
__global__ void __launch_bounds__(256)
convk_mfma(const unsigned short* __restrict__ xt, const unsigned short* __restrict__ wp,
           const float* __restrict__ bias, float* __restrict__ out,
           int OB, int co_off, int do_affine,
           const float* __restrict__ s, const float* __restrict__ o,
           unsigned short* __restrict__ incT)
{
    constexpr int CI = 128;
    constexpr int PAD = K / 2;
    constexpr int RO = 2 - PAD;
    constexpr int MT = 4 / MS;
    constexpr int CO16 = CO >> 4;
    constexpr int CI32 = CI >> 5;
    int tid = threadIdx.x;
    int wave = tid >> 6, lane = tid & 63;
    int h = blockIdx.x / MS, msb = blockIdx.x % MS;
    int b = blockIdx.y;
    int co0 = wave * 16 * NB;
    int n = lane & 15, q = lane >> 4;
    floatx4 acc[MT][NB];
#pragma unroll
    for (int mt = 0; mt < MT; ++mt)
#pragma unroll
        for (int nt = 0; nt < NB; ++nt) acc[mt][nt] = (floatx4){0.f, 0.f, 0.f, 0.f};

    const unsigned short* xb = xt + (size_t)(b * 16) * 4624 * 8;
    int mbase = msb * MT * 16;
    for (int ci0 = 0; ci0 < CI; ci0 += 32) {
#pragma unroll
        for (int kh = 0; kh < K; ++kh) {
            const unsigned short* xrow = xb + (size_t)(((ci0 >> 3) + q) * 4624 + (h + kh + RO) * 68 + RO) * 8;
            const unsigned short* wkh = wp + ((size_t)(kh * K) * CO16 * CI32 + (ci0 >> 5)) * 512 + lane * 8;
#pragma unroll
            for (int kw = 0; kw < K; ++kw) {
                short8 bfr[NB];
#pragma unroll
                for (int nt = 0; nt < NB; ++nt)
                    bfr[nt] = *(const short8*)(wkh + (size_t)((kw * CO16 + (co0 >> 4) + nt) * CI32) * 512);
#pragma unroll
                for (int mt = 0; mt < MT; ++mt) {
                    short8 afr = *(const short8*)(xrow + (mbase + mt * 16 + n + kw) * 8);
#pragma unroll
                    for (int nt = 0; nt < NB; ++nt)
                        acc[mt][nt] = __builtin_amdgcn_mfma_f32_16x16x32_bf16(afr, bfr[nt], acc[mt][nt], 0, 0, 0);
                }
            }
        }
    }
    int px0 = h * 64 + mbase + q * 4;
#pragma unroll
    for (int nt = 0; nt < NB; ++nt) {
        int co = co0 + nt * 16 + n;
        float bi = bias[co];
        float sc = do_affine ? s[co] : 1.f;
        float of = do_affine ? o[co] : 0.f;
        float* ob = out + ((size_t)(b * OB + co_off + co)) * HW;
        unsigned short* tb = incT ? incT + (size_t)b * 524288 : nullptr;
        int cpart = (co >> 5) * 512 + ((co >> 3) & 3) * 128 + (co & 7);
#pragma unroll
        for (int mt = 0; mt < MT; ++mt)
#pragma unroll
            for (int r = 0; r < 4; ++r) {
                int px = px0 + mt * 16 + r;
                float v = acc[mt][nt][r] + bi;
                if (do_affine) v = fmaxf(v, 0.f) * sc + of;
                ob[px] = v;
                if (incT) tb[(size_t)((px >> 4) * 2048 + cpart + (px & 15) * 8)] = f2bf(v);
            }
    }
}

// ---------------- cosine similarity over groups of 128 consecutive floats
__global__ void sim_kernel(const float* __restrict__ r1, const float* __restrict__ r2,
                           float* __restrict__ sim)
{
    int gw = blockIdx.x * 4 + (threadIdx.x >> 6);
    int lane = threadIdx.x & 63;
    int b = gw >> 12, n = gw & 4095;
    const float* p1 = r1 + (size_t)b * 524288 + (size_t)n * 128;
    const float* p2 = r2 + (size_t)b * 524288 + (size_t)n * 128;
    float a0 = p1[lane], a1 = p1[lane + 64];
    float b0 = p2[lane], b1 = p2[lane + 64];
    float dot = a0 * b0 + a1 * b1;
    float n1 = a0 * a0 + a1 * a1;
    float n2 = b0 * b0 + b1 * b1;
    for (int m = 32; m; m >>= 1) {
        dot += __shfl_xor(dot, m);
        n1  += __shfl_xor(n1, m);
        n2  += __shfl_xor(n2, m);
    }
    if (lane == 0) sim[b * 4096 + n] = dot / fmaxf(sqrtf(n1) * sqrtf(n2), 1e-8f);
}

// ---------------- x = concat(dif1, dif2): LDS-transposed, writes A-frag bf16 pack directly
__global__ void __launch_bounds__(256)
x_kernel2(const float* __restrict__ r1, const float* __restrict__ r2,
          const float* __restrict__ sim, unsigned short* __restrict__ xpk)
{
    __shared__ float ls1[32 * 129], ls2[32 * 129];
    int b = blockIdx.y, p0 = blockIdx.x * 32, tid = threadIdx.x;
    const float* F1 = r1 + (size_t)b * 524288;
    const float* F2 = r2 + (size_t)b * 524288;
    for (int i = tid; i < 32 * 128; i += 256) {
        int p = i >> 7, c = i & 127;
        ls1[p * 129 + c] = F1[p0 * 128 + i];
        ls2[p * 129 + c] = F2[p0 * 128 + i];
    }
    __syncthreads();
    for (int j = tid; j < 256 * 32; j += 256) {
        int p = j & 31, cc = j >> 5;
        int c = cc & 127;
        int px = p0 + p;
        float sv = sim[b * 4096 + px];
        const float* F = (cc & 128) ? F2 : F1;
        float t1v = ((cc & 128) ? ls2 : ls1)[p * 129 + c];
        float val = t1v * (1.f - sv) + F[(size_t)c * 4096 + px];
        xpk[(size_t)b * 1048576 + ((size_t)((px >> 4) * 8 + (cc >> 5))) * 512
            + ((cc >> 3) & 3) * 128 + (px & 15) * 8 + (cc & 7)] = f2bf(val);
    }
}

// ---------------- attn = avgpool2(|sim1-sim2|) -> A-frag-packed bf16, channel-split
__global__ void __launch_bounds__(256)
simp_kernel3(const float* __restrict__ r1, const float* __restrict__ r2,
             const float* __restrict__ sim, unsigned short* __restrict__ attn_pk)
{
    __shared__ float lsd[64 * 33];
    int b = blockIdx.y, h2 = blockIdx.x, cg = blockIdx.z, tid = threadIdx.x;
    const float* F1 = r1 + (size_t)b * 524288;
    const float* F2 = r2 + (size_t)b * 524288;
    const float* sb = sim + b * 4096;
    int w2 = tid & 31, cl = tid >> 5;
    float acc[4] = {};
    for (int dh = 0; dh < 2; ++dh) {
        int prow = h2 * 128 + dh * 64;
        __syncthreads();
        for (int i = tid; i < 64 * 32; i += 256) {
            int p = i >> 5, c = i & 31;
            size_t gi = (size_t)(prow + p) * 128 + cg * 32 + c;
            lsd[p * 33 + c] = F1[gi] - F2[gi];
        }
        __syncthreads();
#pragma unroll
        for (int k = 0; k < 4; ++k) {
            int c = cl + 8 * k;
            int cG = cg * 32 + c;
#pragma unroll
            for (int dw = 0; dw < 2; ++dw) {
                int pl = 2 * w2 + dw;
                int p = prow + pl;
                float d = lsd[pl * 33 + c] * sb[p]
                        + (F1[(size_t)cG * 4096 + p] - F2[(size_t)cG * 4096 + p]);
                acc[k] += fabsf(d);
            }
        }
    }
#pragma unroll
    for (int k = 0; k < 4; ++k) {
        int cG = cg * 32 + cl + 8 * k;
        int f = cG * 1024 + h2 * 32 + w2;
        int n = f >> 7, c = f & 127;
        attn_pk[(size_t)b * 131072 + ((n >> 4) * 4 + (c >> 5)) * 512
                + ((c >> 3) & 3) * 128 + (n & 15) * 8 + (c & 7)] = f2bf(acc[k] * 0.25f);
    }
}

// ---------------- attention pass1: 2 n-tiles/block, fused online (max,sum), z-split
__global__ void __launch_bounds__(256)
attnA_pass1(const unsigned short* __restrict__ attn_pk,
            const unsigned short* __restrict__ incT1, const unsigned short* __restrict__ incT2,
            float* __restrict__ pmax, float* __restrict__ psum)
{
    __shared__ float lm[4][32], ls[4][32];
    int pair = blockIdx.y;
    int b = pair & 3, br = pair >> 2;
    int z = blockIdx.z;
    int tid = threadIdx.x;
    int wave = tid >> 6, lane = tid & 63;
    int n0 = blockIdx.x * 32;
    int q = lane >> 4;
    int col = lane & 15;
    const unsigned short* apk = attn_pk + (size_t)b * 131072 + (size_t)blockIdx.x * 4096 + lane * 8;
    short8 afrA[4], afrB[4];
#pragma unroll
    for (int kc = 0; kc < 4; ++kc) {
        afrA[kc] = *(const short8*)(apk + kc * 512);
        afrB[kc] = *(const short8*)(apk + 2048 + kc * 512);
    }
    const unsigned short* ibp = (br ? incT2 : incT1) + (size_t)b * 524288 + lane * 8;
    short8 bbuf[2][4];
    {
        const unsigned short* brow = ibp + (size_t)(z * 64 + wave * 16) * 2048;
#pragma unroll
        for (int kc = 0; kc < 4; ++kc) bbuf[0][kc] = *(const short8*)(brow + kc * 512);
        brow += 2048;
#pragma unroll
        for (int kc = 0; kc < 4; ++kc) bbuf[1][kc] = *(const short8*)(brow + kc * 512);
    }
    float rmA[4], rsA[4], rmB[4], rsB[4];
#pragma unroll
    for (int r = 0; r < 4; ++r) { rmA[r] = -3.0e38f; rsA[r] = 0.f; rmB[r] = -3.0e38f; rsB[r] = 0.f; }
#pragma unroll
    for (int mt = 0; mt < 16; ++mt) {
        const int cur = mt & 1;
        floatx4 accA = (floatx4){0.f, 0.f, 0.f, 0.f};
        floatx4 accB = (floatx4){0.f, 0.f, 0.f, 0.f};
#pragma unroll
        for (int kc = 0; kc < 4; ++kc) {
            accA = __builtin_amdgcn_mfma_f32_16x16x32_bf16(afrA[kc], bbuf[cur][kc], accA, 0, 0, 0);
            accB = __builtin_amdgcn_mfma_f32_16x16x32_bf16(afrB[kc], bbuf[cur][kc], accB, 0, 0, 0);
        }
        if (mt < 14) {
            const unsigned short* brow = ibp + (size_t)(z * 64 + wave * 16 + mt + 2) * 2048;
#pragma unroll
            for (int kc = 0; kc < 4; ++kc) bbuf[cur][kc] = *(const short8*)(brow + kc * 512);
        }
#pragma unroll
        for (int r = 0; r < 4; ++r) {
            float vA = accA[r];
            float nmA = fmaxf(rmA[r], vA);
            rsA[r] = rsA[r] * __expf(rmA[r] - nmA) + __expf(vA - nmA);
            rmA[r] = nmA;
            float vB = accB[r];
            float nmB = fmaxf(rmB[r], vB);
            rsB[r] = rsB[r] * __expf(rmB[r] - nmB) + __expf(vB - nmB);
            rmB[r] = nmB;
        }
    }
#pragma unroll
    for (int d = 1; d < 16; d <<= 1) {
#pragma unroll
        for (int r = 0; r < 4; ++r) {
            float om = __shfl_xor(rmA[r], d);
            float os = __shfl_xor(rsA[r], d);
            float nm = fmaxf(rmA[r], om);
            rsA[r] = rsA[r] * __expf(rmA[r] - nm) + os * __expf(om - nm);
            rmA[r] = nm;
            om = __shfl_xor(rmB[r], d);
            os = __shfl_xor(rsB[r], d);
            nm = fmaxf(rmB[r], om);
            rsB[r] = rsB[r] * __expf(rmB[r] - nm) + os * __expf(om - nm);
            rmB[r] = nm;
        }
    }
    if (col == 0) {
#pragma unroll
        for (int r = 0; r < 4; ++r) {
            lm[wave][q * 4 + r] = rmA[r];      ls[wave][q * 4 + r] = rsA[r];
            lm[wave][16 + q * 4 + r] = rmB[r]; ls[wave][16 + q * 4 + r] = rsB[r];
        }
    }
    __syncthreads();
    if (tid < 32) {
        float bm = lm[0][tid], bs = ls[0][tid];
        for (int w = 1; w < 4; ++w) {
            float om = lm[w][tid], os = ls[w][tid];
            float nm = fmaxf(bm, om);
            bs = bs * __expf(bm - nm) + os * __expf(om - nm);
            bm = nm;
        }
        pmax[((size_t)pair * 4 + z) * 1024 + n0 + tid] = bm;
        psum[((size_t)pair * 4 + z) * 1024 + n0 + tid] = bs;
    }
}

// ---------------- fused: merge z partials (per thread) + scale attn -> attnS_pk; write mx
__global__ void attnA_scale2(const unsigned short* __restrict__ attn_pk,
                             const float* __restrict__ pmax, const float* __restrict__ psum,
                             float* __restrict__ mx, unsigned short* __restrict__ attnS_pk)
{
    int i = blockIdx.x * 256 + threadIdx.x;   // 1,048,576 (coalesced over packed output)
    int pair = i >> 17;
    int o = i & 131071;
    int j = o & 7, lane = (o >> 3) & 63, ct = (o >> 9) & 7, kcn = o >> 12;
    int c = ct * 16 + (lane & 15);
    int n = kcn * 32 + (lane >> 4) * 8 + j;
    int b = pair & 3;
    float bm = pmax[((size_t)pair * 4) * 1024 + n];
    float bs = psum[((size_t)pair * 4) * 1024 + n];
#pragma unroll
    for (int z = 1; z < 4; ++z) {
        float om = pmax[((size_t)pair * 4 + z) * 1024 + n];
        float os = psum[((size_t)pair * 4 + z) * 1024 + n];
        float nm = fmaxf(bm, om);
        bs = bs * __expf(bm - nm) + os * __expf(om - nm);
        bm = nm;
    }
    if (c == 0) mx[pair * 1024 + n] = bm;
    float rc = 1.f / bs;
    int ii = b * 131072 + ((n >> 4) * 4 + (c >> 5)) * 512
           + ((c >> 3) & 3) * 128 + (n & 15) * 8 + (c & 7);
    attnS_pk[(size_t)i] = f2bf(bf2f(attn_pk[ii]) * rc);
}

// ---------------- attention pass B: deep software pipeline, LDS-combined epilogue
// (R9-harness-verified, fp32 abuf out)
__global__ void __launch_bounds__(256)
attn_passB4(const unsigned short* __restrict__ attn_pk,
            const unsigned short* __restrict__ attnS_pk,
            const unsigned short* __restrict__ incT1, const unsigned short* __restrict__ incT2,
            const float* __restrict__ mx,
            const float* __restrict__ inc1, const float* __restrict__ inc2,
            float* __restrict__ abuf)
{
    __shared__ unsigned short lp[4][16 * 36];
    __shared__ float lred[2][2048];
    int pair = blockIdx.y;
    int b = pair & 3, br = pair >> 2;
    int tid = threadIdx.x;
    int wv = tid >> 6, lane = tid & 63;
    int q = lane >> 4, col = lane & 15;
    int msub = wv & 1, nh = wv >> 1;
    int m0 = blockIdx.x * 32 + msub * 16;
    int mtg = m0 >> 4;
    const unsigned short* ibp = (br ? incT2 : incT1) + (size_t)b * 524288 + lane * 8;
    short8 bfrS[4];
#pragma unroll
    for (int kc = 0; kc < 4; ++kc)
        bfrS[kc] = *(const short8*)(ibp + (size_t)(mtg * 4 + kc) * 512);
    const float* mxp = mx + pair * 1024 + nh * 512;
    const unsigned short* aspk = attnS_pk + (size_t)pair * 131072 + lane * 8;
    const unsigned short* apk = attn_pk + (size_t)b * 131072 + lane * 8;
    floatx4 oacc[8];
#pragma unroll
    for (int ct = 0; ct < 8; ++ct) oacc[ct] = (floatx4){0.f, 0.f, 0.f, 0.f};
    unsigned short* lw = lp[wv];

    short8 arP[2][2][4];
    short8 asP[2][8];
    floatx4 mxq[2][2];
    floatx4 sacc[2][2];

#pragma unroll
    for (int t = 0; t < 2; ++t)
#pragma unroll
        for (int kc = 0; kc < 4; ++kc)
            arP[0][t][kc] = *(const short8*)(apk + (size_t)(((nh * 32 + t) * 4 + kc)) * 512);
#pragma unroll
    for (int ct = 0; ct < 8; ++ct)
        asP[0][ct] = *(const short8*)(aspk + (size_t)((nh * 16) * 8 + ct) * 512);
#pragma unroll
    for (int t = 0; t < 2; ++t)
        mxq[0][t] = *(const floatx4*)(mxp + t * 16 + q * 4);
#pragma unroll
    for (int t = 0; t < 2; ++t) {
        floatx4 a = (floatx4){0.f, 0.f, 0.f, 0.f};
#pragma unroll
        for (int kc = 0; kc < 4; ++kc)
            a = __builtin_amdgcn_mfma_f32_16x16x32_bf16(arP[0][t][kc], bfrS[kc], a, 0, 0, 0);
        sacc[0][t] = a;
    }
#pragma unroll
    for (int t = 0; t < 2; ++t)
#pragma unroll
        for (int kc = 0; kc < 4; ++kc)
            arP[1][t][kc] = *(const short8*)(apk + (size_t)(((nh * 32 + 2 + t) * 4 + kc)) * 512);

#pragma unroll
    for (int nc = 0; nc < 16; ++nc) {
        const int cur = nc & 1, nxt = cur ^ 1;
#pragma unroll
        for (int t = 0; t < 2; ++t) {
            floatx4 sv = sacc[cur][t];
            floatx4 mv = mxq[cur][t];
            unsigned int p01 = (unsigned int)f2bf(__expf(sv[0] - mv[0]))
                             | ((unsigned int)f2bf(__expf(sv[1] - mv[1])) << 16);
            unsigned int p23 = (unsigned int)f2bf(__expf(sv[2] - mv[2]))
                             | ((unsigned int)f2bf(__expf(sv[3] - mv[3])) << 16);
            *(uint2*)&lw[col * 36 + t * 16 + q * 4] = make_uint2(p01, p23);
        }
        if (nc < 15) {
#pragma unroll
            for (int ct = 0; ct < 8; ++ct)
                asP[nxt][ct] = *(const short8*)(aspk + (size_t)(((nh * 16 + nc + 1) * 8 + ct)) * 512);
#pragma unroll
            for (int t = 0; t < 2; ++t)
                mxq[nxt][t] = *(const floatx4*)(mxp + (nc + 1) * 32 + t * 16 + q * 4);
        }
        short8 pb = *(const short8*)&lw[col * 36 + q * 8];
        if (nc < 15) {
#pragma unroll
            for (int t = 0; t < 2; ++t) {
                floatx4 a = (floatx4){0.f, 0.f, 0.f, 0.f};
#pragma unroll
                for (int kc = 0; kc < 4; ++kc)
                    a = __builtin_amdgcn_mfma_f32_16x16x32_bf16(arP[nxt][t][kc], bfrS[kc], a, 0, 0, 0);
                sacc[nxt][t] = a;
            }
        }
        if (nc < 14) {
#pragma unroll
            for (int t = 0; t < 2; ++t)
#pragma unroll
                for (int kc = 0; kc < 4; ++kc)
                    arP[cur][t][kc] = *(const short8*)(apk + (size_t)(((nh * 32 + (nc + 2) * 2 + t) * 4 + kc)) * 512);
        }
#pragma unroll
        for (int ct = 0; ct < 8; ++ct)
            oacc[ct] = __builtin_amdgcn_mfma_f32_16x16x32_bf16(asP[cur][ct], pb, oacc[ct], 0, 0, 0);
    }

    if (nh == 1) {
        float* lr = lred[msub];
#pragma unroll
        for (int ct = 0; ct < 8; ++ct)
#pragma unroll
            for (int r = 0; r < 4; ++r)
                lr[(ct * 16 + q * 4 + r) * 16 + col] = oacc[ct][r];
    }
    __syncthreads();
    if (nh == 0) {
        const float* lr = lred[msub];
        const float* resid = (br ? inc2 : inc1) + (size_t)b * 524288;
        float* op = abuf + ((size_t)(b * 256 + br * 128)) * 4096;
        int m = m0 + col;
#pragma unroll
        for (int ct = 0; ct < 8; ++ct)
#pragma unroll
            for (int r = 0; r < 4; ++r) {
                int row = ct * 16 + q * 4 + r;
                op[(size_t)row * 4096 + m] = oacc[ct][r] + lr[row * 16 + col]
                                           + resid[(size_t)row * 4096 + m];
            }
    }
}

// ---------------- bilinear 2x upsample, half-pixel centers, edge clamp
__global__ void upsample_kernel(const float* __restrict__ in, float* __restrict__ out)
{
    int i = blockIdx.x * 256 + threadIdx.x;
    int x = i & 127, y = (i >> 7) & 127, bc = i >> 14;
    const float* ib = in + (size_t)bc * HW;
    float sy = 0.5f * y - 0.25f;
    float sx = 0.5f * x - 0.25f;
    int y0 = (int)floorf(sy); float ty = sy - y0;
    int x0 = (int)floorf(sx); float tx = sx - x0;
    int y0c = min(max(y0, 0), 63), y1c = min(max(y0 + 1, 0), 63);
    int x0c = min(max(x0, 0), 63), x1c = min(max(x0 + 1, 0), 63);
    float v00 = ib[y0c * 64 + x0c], v01 = ib[y0c * 64 + x1c];
    float v10 = ib[y1c * 64 + x0c], v11 = ib[y1c * 64 + x1c];
    out[i] = (1.f - ty) * ((1.f - tx) * v00 + tx * v01) + ty * ((1.f - tx) * v10 + tx * v11);
}

extern "C" void kernel_launch(void* const* d_in, const int* in_sizes, int n_in,
                              void* d_out, int out_size, void* d_ws, size_t ws_size,
                              hipStream_t stream)
{
    const float* t1       = (const float*)d_in[0];
    const float* t2       = (const float*)d_in[1];
    const float* t1_w     = (const float*)d_in[2];
    const float* t1_b     = (const float*)d_in[3];
    const float* t2_w     = (const float*)d_in[4];
    const float* t2_b     = (const float*)d_in[5];
    const float* df_res_w = (const float*)d_in[6];
    const float* df_res_b = (const float*)d_in[7];
    const float* df_res_s = (const float*)d_in[8];
    const float* df_res_o = (const float*)d_in[9];
    const float* df_b0_w  = (const float*)d_in[10];
    const float* df_b0_b  = (const float*)d_in[11];
    const float* df_b0_s  = (const float*)d_in[12];
    const float* df_b0_o  = (const float*)d_in[13];
    const float* df_b1_w  = (const float*)d_in[14];
    const float* df_b1_b  = (const float*)d_in[15];
    const float* df_b1_s  = (const float*)d_in[16];
    const float* df_b1_o  = (const float*)d_in[17];
    const float* df_fu_w  = (const float*)d_in[18];
    const float* df_fu_b  = (const float*)d_in[19];
    const float* df_fu_s  = (const float*)d_in[20];
    const float* df_fu_o  = (const float*)d_in[21];
    const float* br1_w    = (const float*)d_in[22];
    const float* br1_b    = (const float*)d_in[23];
    const float* br2_w    = (const float*)d_in[24];
    const float* br2_b    = (const float*)d_in[25];
    const float* fu_w     = (const float*)d_in[26];
    const float* fu_b     = (const float*)d_in[27];
    const float* fu_s     = (const float*)d_in[28];
    const float* fu_o     = (const float*)d_in[29];

    float* ws = (float*)d_ws;
    float* res1 = ws;                   // 2,097,152 f  (res1 -> r -> inc1 fp32)
    float* res2 = ws + 2097152;         // 2,097,152 f  (res2 -> b01 -> inc2 fp32)
    float* xbuf = ws + 4194304;         // 4,194,304 f  (t1pk/t2pk early; dif; fused at +2M)
    float* scr  = ws + 8388608;         // 4,194,304 f  bf16/f32 scratch region
    float* abuf = ws + 12582912;        // 4,194,304 f  (xpk/b01pk early; concat(a1,a2) late)
    float* attnS_f = ws + 16777216;     // 524,288 f -> wp_t1/t2/res/fu1 early; attnS bf16 (packed)
    float* simv = ws + 17301504;        // 16,384 f (sim early; wp_fu2 late)
    float* mxb  = ws + 17317888;        // 8,192 f

    unsigned short* us     = (unsigned short*)scr;
    unsigned short* wp_b0  = us;                 // 73,728
    unsigned short* wp_b1  = us + 73728;         // 204,800
    unsigned short* wp_br1 = us + 278528;        // 147,456
    unsigned short* wp_br2 = us + 425984;        // 409,600 -> ends 835,584
    unsigned short* xt_r   = us + 851968;        // 2,367,488 -> ends 3,219,456
    unsigned short* xt_dif = us + 3219456;       // 2,367,488 -> ends 5,586,944
    unsigned short* incT1  = us + 5586944;       // 2,097,152 -> ends 7,684,096
    unsigned short* incT2  = us + 851968;        // 2,097,152 (overlays dead xt_r)
    unsigned short* attn_bf= us + 7684096;       // 524,288 -> ends 8,208,384 (f 4,104,192)
    float* scrF = scr;
    float* pmaxb = scrF + 4104192;      // 32,768 f
    float* psumb = scrF + 4136960;      // 32,768 f
    unsigned short* attnS  = (unsigned short*)attnS_f;
    // early-phase overlays (dead before their regions' later use)
    unsigned short* wp_t1  = (unsigned short*)attnS_f;       // 32,768 sh (dead before attnS)
    unsigned short* wp_t2  = wp_t1 + 32768;                  // 32,768 sh
    unsigned short* wp_res = wp_t1 + 65536;                  // 32,768 sh (dead before attnS)
    unsigned short* wp_fu1 = wp_t1 + 98304;                  // 16,384 sh (dead before attnS)
    unsigned short* wp_fu2 = (unsigned short*)simv;          // 32,768 sh (written after simv dead)
    unsigned short* t1pk   = (unsigned short*)xbuf;          // 4,194,304 sh (dead before dif)
    unsigned short* t2pk   = t1pk + 4194304;                 // 4,194,304 sh -> ends at scr
    unsigned short* xpk    = (unsigned short*)abuf;          // 4,194,304 sh (dead before abuf write)
    unsigned short* b01pk  = (unsigned short*)abuf;          // 2,097,152 sh (reuse; xpk dead first)
    unsigned short* abufpk = us;                             // 4,194,304 sh (scr all dead post-attn)

    dim3 blk(256);

    // fused: zero padded bf16 conv inputs + prepack all conv + t1/t2 1x1 weights
    setup_kernel<<<5832, blk, 0, stream>>>((uint4*)xt_r, 591872,
                                           df_b0_w, wp_b0, df_b1_w, wp_b1,
                                           br1_w, wp_br1, br2_w, wp_br2,
                                           t1_w, wp_t1, t2_w, wp_t2);
    // pack t1/t2 to A-frag bf16
    packX<8><<<16384, blk, 0, stream>>>(t1, t1pk);
    packX<8><<<16384, blk, 0, stream>>>(t2, t2pk);

    // res1/res2 = 1x1 conv(t1/t2) via MFMA GEMM
    gemm1x1<8><<<dim3(256, 4), blk, 0, stream>>>(t1pk, wp_t1, t1_b, res1, 0, nullptr, nullptr, nullptr, nullptr);
    gemm1x1<8><<<dim3(256, 4), blk, 0, stream>>>(t2pk, wp_t2, t2_b, res2, 0, nullptr, nullptr, nullptr, nullptr);
    sim_kernel<<<4096, blk, 0, stream>>>(res1, res2, simv);
    x_kernel2<<<dim3(128, 4), blk, 0, stream>>>(res1, res2, simv, xpk);   // writes packed x directly
    simp_kernel3<<<dim3(32, 4, 4), blk, 0, stream>>>(res1, res2, simv, attn_bf);
    // late weight prepack (simv now dead; attnS region still free)
    prepack3<<<320, blk, 0, stream>>>(df_res_w, wp_res, df_fu_w, wp_fu1, fu_w, wp_fu2);
    // r = stdconv1x1(x) via MFMA GEMM (+ bf16 padded chunked copy)
    gemm1x1<8><<<dim3(256, 4), blk, 0, stream>>>(xpk, wp_res, df_res_b, res1, 1, df_res_s, df_res_o, nullptr, xt_r);
    // b0 3x3 -> res2[0:64], b1 5x5 -> res2[64:128]
    convk_mfma<3, 64, 1, 4><<<dim3(256, 4), blk, 0, stream>>>(xt_r, wp_b0, df_b0_b, res2, 128, 0, 1, df_b0_s, df_b0_o, nullptr);
    convk_mfma<5, 64, 1, 4><<<dim3(256, 4), blk, 0, stream>>>(xt_r, wp_b1, df_b1_b, res2, 128, 64, 1, df_b1_s, df_b1_o, nullptr);
    // dif = stdconv1x1(b01) + r via MFMA GEMM (+ bf16 padded chunked copy)
    packX<4><<<8192, blk, 0, stream>>>(res2, b01pk);
    gemm1x1<4><<<dim3(256, 4), blk, 0, stream>>>(b01pk, wp_fu1, df_fu_b, xbuf, 1, df_fu_s, df_fu_o, res1, xt_dif);
    // inc1/inc2 (fp32 + bf16 B-frag-packed incT)
    convk_mfma<3, 128, 2, 4><<<dim3(256, 4), blk, 0, stream>>>(xt_dif, wp_br1, br1_b, res1, 128, 0, 0, nullptr, nullptr, incT1);
    convk_mfma<5, 128, 2, 4><<<dim3(256, 4), blk, 0, stream>>>(xt_dif, wp_br2, br2_b, res2, 128, 0, 0, nullptr, nullptr, incT2);
    // attention
    attnA_pass1<<<dim3(32, 8, 4), blk, 0, stream>>>(attn_bf, incT1, incT2, pmaxb, psumb);
    attnA_scale2<<<4096, blk, 0, stream>>>(attn_bf, pmaxb, psumb, mxb, attnS);
    attn_passB4<<<dim3(128, 8), blk, 0, stream>>>(attn_bf, attnS, incT1, incT2, mxb, res1, res2, abuf);
    // fused = stdconv1x1(concat(a1,a2)) + dif via MFMA GEMM
    float* dif = xbuf;
    float* fused = xbuf + 2097152;
    packX<8><<<16384, blk, 0, stream>>>(abuf, abufpk);
    gemm1x1<8><<<dim3(256, 4), blk, 0, stream>>>(abufpk, wp_fu2, fu_b, fused, 1, fu_s, fu_o, dif, nullptr);
    // bilinear 2x upsample -> d_out
    upsample_kernel<<<32768, blk, 0, stream>>>(fused, (float*)d_out);
}

// Round 14
// 451.500 us; speedup vs baseline: 1.2144x; 1.0034x over previous
//
#include <hip/hip_runtime.h>
#include <math.h>

#define HW 4096   // 64*64

typedef __attribute__((ext_vector_type(8))) short short8;
typedef __attribute__((ext_vector_type(4))) float floatx4;
typedef __attribute__((ext_vector_type(2))) float floatx2;

__device__ inline unsigned short f2bf(float f) {
    unsigned int u = __float_as_uint(f);
    unsigned int r = (u + 0x7fffu + ((u >> 16) & 1u)) >> 16;
    return (unsigned short)r;
}
__device__ inline float bf2f(unsigned short u) {
    return __uint_as_float(((unsigned int)u) << 16);
}

// Fragment-pack index helpers.
// A-frag pack of matrix M[R rows][K cols]: element (r,k) at
//   tile(r>>4, k>>5)*512 + ((k>>3)&3)*128 + (r&15)*8 + (k&7); wave loads base + tile*512 + lane*8.
// xt (conv activations) layout: [b][ci>>3][row(68)][col(68)][ci&7].

// ---------------- device helpers: weight prepack + activation pack
__device__ inline void prepack_dev(const float* __restrict__ w, unsigned short* __restrict__ wp,
                                   int CO, int CI, int KK, int i)
{
    if (i >= CO * CI * KK) return;
    int ci = i % CI;
    int t = i / CI;
    int co = t % CO;
    int kk = t / CO;
    int ti = (kk * (CO >> 4) + (co >> 4)) * (CI >> 5) + (ci >> 5);
    wp[(size_t)ti * 512 + ((ci >> 3) & 3) * 128 + (co & 15) * 8 + (ci & 7)]
        = f2bf(w[(co * CI + ci) * KK + kk]);
}

__device__ inline void packX_dev(const float* __restrict__ in, unsigned short* __restrict__ out,
                                 int CI32, int i)
{
    int b = i / (CI32 * 131072);
    int j = i % (CI32 * 131072);
    int ci = j >> 12, px = j & 4095;
    out[(size_t)b * (CI32 * 131072) + ((size_t)((px >> 4) * CI32 + (ci >> 5))) * 512
        + ((ci >> 3) & 3) * 128 + (px & 15) * 8 + (ci & 7)] = f2bf(in[i]);
}

// ---------------- fused setup: zero padded xt + 6 weight prepacks + t1/t2 packs
__global__ void setup_kernel(uint4* __restrict__ zp, int zn,
                             const float* __restrict__ w0, unsigned short* __restrict__ wp0,
                             const float* __restrict__ w1, unsigned short* __restrict__ wp1,
                             const float* __restrict__ w2, unsigned short* __restrict__ wp2,
                             const float* __restrict__ w3, unsigned short* __restrict__ wp3,
                             const float* __restrict__ w4, unsigned short* __restrict__ wp4,
                             const float* __restrict__ w5, unsigned short* __restrict__ wp5,
                             const float* __restrict__ t1, unsigned short* __restrict__ t1pk,
                             const float* __restrict__ t2, unsigned short* __restrict__ t2pk)
{
    int bx = blockIdx.x, tid = threadIdx.x;
    if (bx < 2312) {
        int i = bx * 256 + tid;
        if (i < zn) zp[i] = make_uint4(0u, 0u, 0u, 0u);
    } else if (bx < 2600) {
        prepack_dev(w0, wp0, 64, 128, 9,  (bx - 2312) * 256 + tid);
    } else if (bx < 3400) {
        prepack_dev(w1, wp1, 64, 128, 25, (bx - 2600) * 256 + tid);
    } else if (bx < 3976) {
        prepack_dev(w2, wp2, 128, 128, 9, (bx - 3400) * 256 + tid);
    } else if (bx < 5576) {
        prepack_dev(w3, wp3, 128, 128, 25,(bx - 3976) * 256 + tid);
    } else if (bx < 5704) {
        prepack_dev(w4, wp4, 128, 256, 1, (bx - 5576) * 256 + tid);
    } else if (bx < 5832) {
        prepack_dev(w5, wp5, 128, 256, 1, (bx - 5704) * 256 + tid);
    } else if (bx < 22216) {
        packX_dev(t1, t1pk, 8, (bx - 5832) * 256 + tid);
    } else {
        packX_dev(t2, t2pk, 8, (bx - 22216) * 256 + tid);
    }
}

// ---------------- late prepack: 1x1 weights needed after early buffers die
__global__ void prepack3(const float* __restrict__ w0, unsigned short* __restrict__ p0,
                         const float* __restrict__ w1, unsigned short* __restrict__ p1,
                         const float* __restrict__ w2, unsigned short* __restrict__ p2)
{
    int bx = blockIdx.x, tid = threadIdx.x;
    if (bx < 128)      prepack_dev(w0, p0, 128, 256, 1, bx * 256 + tid);
    else if (bx < 192) prepack_dev(w1, p1, 128, 128, 1, (bx - 128) * 256 + tid);
    else               prepack_dev(w2, p2, 128, 256, 1, (bx - 192) * 256 + tid);
}

// ---------------- pack fp32 [b][CI][4096px] -> A-frag-packed bf16 (px rows, ci k)
template<int CI32>
__global__ void packX(const float* __restrict__ in, unsigned short* __restrict__ out)
{
    int i = blockIdx.x * 256 + threadIdx.x;
    packX_dev(in, out, CI32, i);
}

// ---------------- 1x1 conv (CO=128) as bf16 MFMA GEMM: out = affine(W*X+b) [+addbuf] [+xt]
template<int KC>   // KC = CI/32
__global__ void __launch_bounds__(256)
gemm1x1(const unsigned short* __restrict__ Xpk, const unsigned short* __restrict__ Wpk,
        const float* __restrict__ bias, float* __restrict__ out,
        int do_affine, const float* __restrict__ s, const float* __restrict__ o,
        const float* __restrict__ addbuf, unsigned short* __restrict__ xt)
{
    int tid = threadIdx.x;
    int wv = tid >> 6, lane = tid & 63;
    int q = lane >> 4, n = lane & 15;
    int pxb = blockIdx.x;                       // 256 px-tiles of 16
    int b = blockIdx.y;
    int co0 = wv * 32;
    const unsigned short* apk = Xpk + (size_t)b * (KC * 131072) + (size_t)pxb * KC * 512 + lane * 8;
    const unsigned short* wpk = Wpk + (size_t)(co0 >> 4) * KC * 512 + lane * 8;
    floatx4 acc0 = (floatx4){0.f, 0.f, 0.f, 0.f};
    floatx4 acc1 = (floatx4){0.f, 0.f, 0.f, 0.f};
#pragma unroll
    for (int kc = 0; kc < KC; ++kc) {
        short8 a  = *(const short8*)(apk + kc * 512);
        short8 b0 = *(const short8*)(wpk + kc * 512);
        short8 b1 = *(const short8*)(wpk + (KC + kc) * 512);
        acc0 = __builtin_amdgcn_mfma_f32_16x16x32_bf16(a, b0, acc0, 0, 0, 0);
        acc1 = __builtin_amdgcn_mfma_f32_16x16x32_bf16(a, b1, acc1, 0, 0, 0);
    }
    int px0 = pxb * 16 + q * 4;
#pragma unroll
    for (int nt = 0; nt < 2; ++nt) {
        int co = co0 + nt * 16 + n;
        float bi = bias[co];
        float sc = do_affine ? s[co] : 1.f;
        float of = do_affine ? o[co] : 0.f;
        floatx4 v = nt ? acc1 : acc0;
        floatx4 res;
        if (addbuf) res = *(const floatx4*)(addbuf + ((size_t)(b * 128 + co)) * 4096 + px0);
#pragma unroll
        for (int r = 0; r < 4; ++r) {
            float val = v[r] + bi;
            if (do_affine) val = fmaxf(val, 0.f) * sc + of;
            if (addbuf) val += res[r];
            v[r] = val;
        }
        *(floatx4*)(out + ((size_t)(b * 128 + co)) * 4096 + px0) = v;
        if (xt) {
            unsigned short* xb = xt + ((size_t)(b * 16 + (co >> 3)) * 4624) * 8 + (co & 7);
#pragma unroll
            for (int r = 0; r < 4; ++r) {
                int px = px0 + r;
                int h = px >> 6, wc = px & 63;
                xb[(size_t)((h + 2) * 68 + (wc + 2)) * 8] = f2bf(v[r]);
            }
        }
    }
}

// ---------------- KxK conv as implicit-GEMM bf16 MFMA, m-split MS for occupancy
// (R9-verified: incT B-frag pack with hardcoded 2048, local-co cpart)
template<int K, int CO, int NB, int MS>
__global__ void __launch_bounds__(256)
convk_mfma(const unsigned short* __restrict__ xt, const unsigned short* __restrict__ wp,
           const float* __restrict__ bias, float* __restrict__ out,
           int OB, int co_off, int do_affine,
           const float* __restrict__ s, const float* __restrict__ o,
           unsigned short* __restrict__ incT)
{
    constexpr int CI = 128;
    constexpr int PAD = K / 2;
    constexpr int RO = 2 - PAD;
    constexpr int MT = 4 / MS;
    constexpr int CO16 = CO >> 4;
    constexpr int CI32 = CI >> 5;
    int tid = threadIdx.x;
    int wave = tid >> 6, lane = tid & 63;
    int h = blockIdx.x / MS, msb = blockIdx.x % MS;
    int b = blockIdx.y;
    int co0 = wave * 16 * NB;
    int n = lane & 15, q = lane >> 4;
    floatx4 acc[MT][NB];
#pragma unroll
    for (int mt = 0; mt < MT; ++mt)
#pragma unroll
        for (int nt = 0; nt < NB; ++nt) acc[mt][nt] = (floatx4){0.f, 0.f, 0.f, 0.f};

    const unsigned short* xb = xt + (size_t)(b * 16) * 4624 * 8;
    int mbase = msb * MT * 16;
    for (int ci0 = 0; ci0 < CI; ci0 += 32) {
#pragma unroll
        for (int kh = 0; kh < K; ++kh) {
            const unsigned short* xrow = xb + (size_t)(((ci0 >> 3) + q) * 4624 + (h + kh + RO) * 68 + RO) * 8;
            const unsigned short* wkh = wp + ((size_t)(kh * K) * CO16 * CI32 + (ci0 >> 5)) * 512 + lane * 8;
#pragma unroll
            for (int kw = 0; kw < K; ++kw) {
                short8 bfr[NB];
#pragma unroll
                for (int nt = 0; nt < NB; ++nt)
                    bfr[nt] = *(const short8*)(wkh + (size_t)((kw * CO16 + (co0 >> 4) + nt) * CI32) * 512);
#pragma unroll
                for (int mt = 0; mt < MT; ++mt) {
                    short8 afr = *(const short8*)(xrow + (mbase + mt * 16 + n + kw) * 8);
#pragma unroll
                    for (int nt = 0; nt < NB; ++nt)
                        acc[mt][nt] = __builtin_amdgcn_mfma_f32_16x16x32_bf16(afr, bfr[nt], acc[mt][nt], 0, 0, 0);
                }
            }
        }
    }
    int px0 = h * 64 + mbase + q * 4;
#pragma unroll
    for (int nt = 0; nt < NB; ++nt) {
        int co = co0 + nt * 16 + n;
        float bi = bias[co];
        float sc = do_affine ? s[co] : 1.f;
        float of = do_affine ? o[co] : 0.f;
        float* ob = out + ((size_t)(b * OB + co_off + co)) * HW;
        unsigned short* tb = incT ? incT + (size_t)b * 524288 : nullptr;
        int cpart = (co >> 5) * 512 + ((co >> 3) & 3) * 128 + (co & 7);
#pragma unroll
        for (int mt = 0; mt < MT; ++mt)
#pragma unroll
            for (int r = 0; r < 4; ++r) {
                int px = px0 + mt * 16 + r;
                float v = acc[mt][nt][r] + bi;
                if (do_affine) v = fmaxf(v, 0.f) * sc + of;
                ob[px] = v;
                if (incT) tb[(size_t)((px >> 4) * 2048 + cpart + (px & 15) * 8)] = f2bf(v);
            }
    }
}

// ---------------- cosine similarity over groups of 128 consecutive floats
__global__ void sim_kernel(const float* __restrict__ r1, const float* __restrict__ r2,
                           float* __restrict__ sim)
{
    int gw = blockIdx.x * 4 + (threadIdx.x >> 6);
    int lane = threadIdx.x & 63;
    int b = gw >> 12, n = gw & 4095;
    const float* p1 = r1 + (size_t)b * 524288 + (size_t)n * 128;
    const float* p2 = r2 + (size_t)b * 524288 + (size_t)n * 128;
    float a0 = p1[lane], a1 = p1[lane + 64];
    float b0 = p2[lane], b1 = p2[lane + 64];
    float dot = a0 * b0 + a1 * b1;
    float n1 = a0 * a0 + a1 * a1;
    float n2 = b0 * b0 + b1 * b1;
    for (int m = 32; m; m >>= 1) {
        dot += __shfl_xor(dot, m);
        n1  += __shfl_xor(n1, m);
        n2  += __shfl_xor(n2, m);
    }
    if (lane == 0) sim[b * 4096 + n] = dot / fmaxf(sqrtf(n1) * sqrtf(n2), 1e-8f);
}

// ---------------- x = concat(dif1, dif2): LDS-transposed, writes A-frag bf16 pack directly
__global__ void __launch_bounds__(256)
x_kernel2(const float* __restrict__ r1, const float* __restrict__ r2,
          const float* __restrict__ sim, unsigned short* __restrict__ xpk)
{
    __shared__ float ls1[32 * 129], ls2[32 * 129];
    int b = blockIdx.y, p0 = blockIdx.x * 32, tid = threadIdx.x;
    const float* F1 = r1 + (size_t)b * 524288;
    const float* F2 = r2 + (size_t)b * 524288;
    for (int i = tid; i < 32 * 128; i += 256) {
        int p = i >> 7, c = i & 127;
        ls1[p * 129 + c] = F1[p0 * 128 + i];
        ls2[p * 129 + c] = F2[p0 * 128 + i];
    }
    __syncthreads();
    for (int j = tid; j < 256 * 32; j += 256) {
        int p = j & 31, cc = j >> 5;
        int c = cc & 127;
        int px = p0 + p;
        float sv = sim[b * 4096 + px];
        const float* F = (cc & 128) ? F2 : F1;
        float t1v = ((cc & 128) ? ls2 : ls1)[p * 129 + c];
        float val = t1v * (1.f - sv) + F[(size_t)c * 4096 + px];
        xpk[(size_t)b * 1048576 + ((size_t)((px >> 4) * 8 + (cc >> 5))) * 512
            + ((cc >> 3) & 3) * 128 + (px & 15) * 8 + (cc & 7)] = f2bf(val);
    }
}

// ---------------- attn = avgpool2(|sim1-sim2|) -> A-frag-packed bf16, channel-split
__global__ void __launch_bounds__(256)
simp_kernel3(const float* __restrict__ r1, const float* __restrict__ r2,
             const float* __restrict__ sim, unsigned short* __restrict__ attn_pk)
{
    __shared__ float lsd[64 * 33];
    int b = blockIdx.y, h2 = blockIdx.x, cg = blockIdx.z, tid = threadIdx.x;
    const float* F1 = r1 + (size_t)b * 524288;
    const float* F2 = r2 + (size_t)b * 524288;
    const float* sb = sim + b * 4096;
    int w2 = tid & 31, cl = tid >> 5;
    float acc[4] = {};
    for (int dh = 0; dh < 2; ++dh) {
        int prow = h2 * 128 + dh * 64;
        __syncthreads();
        for (int i = tid; i < 64 * 32; i += 256) {
            int p = i >> 5, c = i & 31;
            size_t gi = (size_t)(prow + p) * 128 + cg * 32 + c;
            lsd[p * 33 + c] = F1[gi] - F2[gi];
        }
        __syncthreads();
#pragma unroll
        for (int k = 0; k < 4; ++k) {
            int c = cl + 8 * k;
            int cG = cg * 32 + c;
#pragma unroll
            for (int dw = 0; dw < 2; ++dw) {
                int pl = 2 * w2 + dw;
                int p = prow + pl;
                float d = lsd[pl * 33 + c] * sb[p]
                        + (F1[(size_t)cG * 4096 + p] - F2[(size_t)cG * 4096 + p]);
                acc[k] += fabsf(d);
            }
        }
    }
#pragma unroll
    for (int k = 0; k < 4; ++k) {
        int cG = cg * 32 + cl + 8 * k;
        int f = cG * 1024 + h2 * 32 + w2;
        int n = f >> 7, c = f & 127;
        attn_pk[(size_t)b * 131072 + ((n >> 4) * 4 + (c >> 5)) * 512
                + ((c >> 3) & 3) * 128 + (n & 15) * 8 + (c & 7)] = f2bf(acc[k] * 0.25f);
    }
}

// ---------------- attention pass1: 2 n-tiles/block, fused online (max,sum), z-split
__global__ void __launch_bounds__(256)
attnA_pass1(const unsigned short* __restrict__ attn_pk,
            const unsigned short* __restrict__ incT1, const unsigned short* __restrict__ incT2,
            float* __restrict__ pmax, float* __restrict__ psum)
{
    __shared__ float lm[4][32], ls[4][32];
    int pair = blockIdx.y;
    int b = pair & 3, br = pair >> 2;
    int z = blockIdx.z;
    int tid = threadIdx.x;
    int wave = tid >> 6, lane = tid & 63;
    int n0 = blockIdx.x * 32;
    int q = lane >> 4;
    int col = lane & 15;
    const unsigned short* apk = attn_pk + (size_t)b * 131072 + (size_t)blockIdx.x * 4096 + lane * 8;
    short8 afrA[4], afrB[4];
#pragma unroll
    for (int kc = 0; kc < 4; ++kc) {
        afrA[kc] = *(const short8*)(apk + kc * 512);
        afrB[kc] = *(const short8*)(apk + 2048 + kc * 512);
    }
    const unsigned short* ibp = (br ? incT2 : incT1) + (size_t)b * 524288 + lane * 8;
    short8 bbuf[2][4];
    {
        const unsigned short* brow = ibp + (size_t)(z * 64 + wave * 16) * 2048;
#pragma unroll
        for (int kc = 0; kc < 4; ++kc) bbuf[0][kc] = *(const short8*)(brow + kc * 512);
        brow += 2048;
#pragma unroll
        for (int kc = 0; kc < 4; ++kc) bbuf[1][kc] = *(const short8*)(brow + kc * 512);
    }
    float rmA[4], rsA[4], rmB[4], rsB[4];
#pragma unroll
    for (int r = 0; r < 4; ++r) { rmA[r] = -3.0e38f; rsA[r] = 0.f; rmB[r] = -3.0e38f; rsB[r] = 0.f; }
#pragma unroll
    for (int mt = 0; mt < 16; ++mt) {
        const int cur = mt & 1;
        floatx4 accA = (floatx4){0.f, 0.f, 0.f, 0.f};
        floatx4 accB = (floatx4){0.f, 0.f, 0.f, 0.f};
#pragma unroll
        for (int kc = 0; kc < 4; ++kc) {
            accA = __builtin_amdgcn_mfma_f32_16x16x32_bf16(afrA[kc], bbuf[cur][kc], accA, 0, 0, 0);
            accB = __builtin_amdgcn_mfma_f32_16x16x32_bf16(afrB[kc], bbuf[cur][kc], accB, 0, 0, 0);
        }
        if (mt < 14) {
            const unsigned short* brow = ibp + (size_t)(z * 64 + wave * 16 + mt + 2) * 2048;
#pragma unroll
            for (int kc = 0; kc < 4; ++kc) bbuf[cur][kc] = *(const short8*)(brow + kc * 512);
        }
#pragma unroll
        for (int r = 0; r < 4; ++r) {
            float vA = accA[r];
            float nmA = fmaxf(rmA[r], vA);
            rsA[r] = rsA[r] * __expf(rmA[r] - nmA) + __expf(vA - nmA);
            rmA[r] = nmA;
            float vB = accB[r];
            float nmB = fmaxf(rmB[r], vB);
            rsB[r] = rsB[r] * __expf(rmB[r] - nmB) + __expf(vB - nmB);
            rmB[r] = nmB;
        }
    }
#pragma unroll
    for (int d = 1; d < 16; d <<= 1) {
#pragma unroll
        for (int r = 0; r < 4; ++r) {
            float om = __shfl_xor(rmA[r], d);
            float os = __shfl_xor(rsA[r], d);
            float nm = fmaxf(rmA[r], om);
            rsA[r] = rsA[r] * __expf(rmA[r] - nm) + os * __expf(om - nm);
            rmA[r] = nm;
            om = __shfl_xor(rmB[r], d);
            os = __shfl_xor(rsB[r], d);
            nm = fmaxf(rmB[r], om);
            rsB[r] = rsB[r] * __expf(rmB[r] - nm) + os * __expf(om - nm);
            rmB[r] = nm;
        }
    }
    if (col == 0) {
#pragma unroll
        for (int r = 0; r < 4; ++r) {
            lm[wave][q * 4 + r] = rmA[r];      ls[wave][q * 4 + r] = rsA[r];
            lm[wave][16 + q * 4 + r] = rmB[r]; ls[wave][16 + q * 4 + r] = rsB[r];
        }
    }
    __syncthreads();
    if (tid < 32) {
        float bm = lm[0][tid], bs = ls[0][tid];
        for (int w = 1; w < 4; ++w) {
            float om = lm[w][tid], os = ls[w][tid];
            float nm = fmaxf(bm, om);
            bs = bs * __expf(bm - nm) + os * __expf(om - nm);
            bm = nm;
        }
        pmax[((size_t)pair * 4 + z) * 1024 + n0 + tid] = bm;
        psum[((size_t)pair * 4 + z) * 1024 + n0 + tid] = bs;
    }
}

// ---------------- fused: merge z partials (per thread) + scale attn -> attnS_pk; write mx
__global__ void attnA_scale2(const unsigned short* __restrict__ attn_pk,
                             const float* __restrict__ pmax, const float* __restrict__ psum,
                             float* __restrict__ mx, unsigned short* __restrict__ attnS_pk)
{
    int i = blockIdx.x * 256 + threadIdx.x;   // 1,048,576 (coalesced over packed output)
    int pair = i >> 17;
    int o = i & 131071;
    int j = o & 7, lane = (o >> 3) & 63, ct = (o >> 9) & 7, kcn = o >> 12;
    int c = ct * 16 + (lane & 15);
    int n = kcn * 32 + (lane >> 4) * 8 + j;
    int b = pair & 3;
    float bm = pmax[((size_t)pair * 4) * 1024 + n];
    float bs = psum[((size_t)pair * 4) * 1024 + n];
#pragma unroll
    for (int z = 1; z < 4; ++z) {
        float om = pmax[((size_t)pair * 4 + z) * 1024 + n];
        float os = psum[((size_t)pair * 4 + z) * 1024 + n];
        float nm = fmaxf(bm, om);
        bs = bs * __expf(bm - nm) + os * __expf(om - nm);
        bm = nm;
    }
    if (c == 0) mx[pair * 1024 + n] = bm;
    float rc = 1.f / bs;
    int ii = b * 131072 + ((n >> 4) * 4 + (c >> 5)) * 512
           + ((c >> 3) & 3) * 128 + (n & 15) * 8 + (c & 7);
    attnS_pk[(size_t)i] = f2bf(bf2f(attn_pk[ii]) * rc);
}

// ---------------- attention pass B: deep software pipeline, LDS-combined epilogue
// (R12-harness-verified, fp32 abuf out)
__global__ void __launch_bounds__(256)
attn_passB4(const unsigned short* __restrict__ attn_pk,
            const unsigned short* __restrict__ attnS_pk,
            const unsigned short* __restrict__ incT1, const unsigned short* __restrict__ incT2,
            const float* __restrict__ mx,
            const float* __restrict__ inc1, const float* __restrict__ inc2,
            float* __restrict__ abuf)
{
    __shared__ unsigned short lp[4][16 * 36];
    __shared__ float lred[2][2048];
    int pair = blockIdx.y;
    int b = pair & 3, br = pair >> 2;
    int tid = threadIdx.x;
    int wv = tid >> 6, lane = tid & 63;
    int q = lane >> 4, col = lane & 15;
    int msub = wv & 1, nh = wv >> 1;
    int m0 = blockIdx.x * 32 + msub * 16;
    int mtg = m0 >> 4;
    const unsigned short* ibp = (br ? incT2 : incT1) + (size_t)b * 524288 + lane * 8;
    short8 bfrS[4];
#pragma unroll
    for (int kc = 0; kc < 4; ++kc)
        bfrS[kc] = *(const short8*)(ibp + (size_t)(mtg * 4 + kc) * 512);
    const float* mxp = mx + pair * 1024 + nh * 512;
    const unsigned short* aspk = attnS_pk + (size_t)pair * 131072 + lane * 8;
    const unsigned short* apk = attn_pk + (size_t)b * 131072 + lane * 8;
    floatx4 oacc[8];
#pragma unroll
    for (int ct = 0; ct < 8; ++ct) oacc[ct] = (floatx4){0.f, 0.f, 0.f, 0.f};
    unsigned short* lw = lp[wv];

    short8 arP[2][2][4];
    short8 asP[2][8];
    floatx4 mxq[2][2];
    floatx4 sacc[2][2];

#pragma unroll
    for (int t = 0; t < 2; ++t)
#pragma unroll
        for (int kc = 0; kc < 4; ++kc)
            arP[0][t][kc] = *(const short8*)(apk + (size_t)(((nh * 32 + t) * 4 + kc)) * 512);
#pragma unroll
    for (int ct = 0; ct < 8; ++ct)
        asP[0][ct] = *(const short8*)(aspk + (size_t)((nh * 16) * 8 + ct) * 512);
#pragma unroll
    for (int t = 0; t < 2; ++t)
        mxq[0][t] = *(const floatx4*)(mxp + t * 16 + q * 4);
#pragma unroll
    for (int t = 0; t < 2; ++t) {
        floatx4 a = (floatx4){0.f, 0.f, 0.f, 0.f};
#pragma unroll
        for (int kc = 0; kc < 4; ++kc)
            a = __builtin_amdgcn_mfma_f32_16x16x32_bf16(arP[0][t][kc], bfrS[kc], a, 0, 0, 0);
        sacc[0][t] = a;
    }
#pragma unroll
    for (int t = 0; t < 2; ++t)
#pragma unroll
        for (int kc = 0; kc < 4; ++kc)
            arP[1][t][kc] = *(const short8*)(apk + (size_t)(((nh * 32 + 2 + t) * 4 + kc)) * 512);

#pragma unroll
    for (int nc = 0; nc < 16; ++nc) {
        const int cur = nc & 1, nxt = cur ^ 1;
#pragma unroll
        for (int t = 0; t < 2; ++t) {
            floatx4 sv = sacc[cur][t];
            floatx4 mv = mxq[cur][t];
            unsigned int p01 = (unsigned int)f2bf(__expf(sv[0] - mv[0]))
                             | ((unsigned int)f2bf(__expf(sv[1] - mv[1])) << 16);
            unsigned int p23 = (unsigned int)f2bf(__expf(sv[2] - mv[2]))
                             | ((unsigned int)f2bf(__expf(sv[3] - mv[3])) << 16);
            *(uint2*)&lw[col * 36 + t * 16 + q * 4] = make_uint2(p01, p23);
        }
        if (nc < 15) {
#pragma unroll
            for (int ct = 0; ct < 8; ++ct)
                asP[nxt][ct] = *(const short8*)(aspk + (size_t)(((nh * 16 + nc + 1) * 8 + ct)) * 512);
#pragma unroll
            for (int t = 0; t < 2; ++t)
                mxq[nxt][t] = *(const floatx4*)(mxp + (nc + 1) * 32 + t * 16 + q * 4);
        }
        short8 pb = *(const short8*)&lw[col * 36 + q * 8];
        if (nc < 15) {
#pragma unroll
            for (int t = 0; t < 2; ++t) {
                floatx4 a = (floatx4){0.f, 0.f, 0.f, 0.f};
#pragma unroll
                for (int kc = 0; kc < 4; ++kc)
                    a = __builtin_amdgcn_mfma_f32_16x16x32_bf16(arP[nxt][t][kc], bfrS[kc], a, 0, 0, 0);
                sacc[nxt][t] = a;
            }
        }
        if (nc < 14) {
#pragma unroll
            for (int t = 0; t < 2; ++t)
#pragma unroll
                for (int kc = 0; kc < 4; ++kc)
                    arP[cur][t][kc] = *(const short8*)(apk + (size_t)(((nh * 32 + (nc + 2) * 2 + t) * 4 + kc)) * 512);
        }
#pragma unroll
        for (int ct = 0; ct < 8; ++ct)
            oacc[ct] = __builtin_amdgcn_mfma_f32_16x16x32_bf16(asP[cur][ct], pb, oacc[ct], 0, 0, 0);
    }

    if (nh == 1) {
        float* lr = lred[msub];
#pragma unroll
        for (int ct = 0; ct < 8; ++ct)
#pragma unroll
            for (int r = 0; r < 4; ++r)
                lr[(ct * 16 + q * 4 + r) * 16 + col] = oacc[ct][r];
    }
    __syncthreads();
    if (nh == 0) {
        const float* lr = lred[msub];
        const float* resid = (br ? inc2 : inc1) + (size_t)b * 524288;
        float* op = abuf + ((size_t)(b * 256 + br * 128)) * 4096;
        int m = m0 + col;
#pragma unroll
        for (int ct = 0; ct < 8; ++ct)
#pragma unroll
            for (int r = 0; r < 4; ++r) {
                int row = ct * 16 + q * 4 + r;
                op[(size_t)row * 4096 + m] = oacc[ct][r] + lr[row * 16 + col]
                                           + resid[(size_t)row * 4096 + m];
            }
    }
}

// ---------------- bilinear 2x upsample, half-pixel centers, edge clamp
__global__ void upsample_kernel(const float* __restrict__ in, float* __restrict__ out)
{
    int i = blockIdx.x * 256 + threadIdx.x;
    int x = i & 127, y = (i >> 7) & 127, bc = i >> 14;
    const float* ib = in + (size_t)bc * HW;
    float sy = 0.5f * y - 0.25f;
    float sx = 0.5f * x - 0.25f;
    int y0 = (int)floorf(sy); float ty = sy - y0;
    int x0 = (int)floorf(sx); float tx = sx - x0;
    int y0c = min(max(y0, 0), 63), y1c = min(max(y0 + 1, 0), 63);
    int x0c = min(max(x0, 0), 63), x1c = min(max(x0 + 1, 0), 63);
    float v00 = ib[y0c * 64 + x0c], v01 = ib[y0c * 64 + x1c];
    float v10 = ib[y1c * 64 + x0c], v11 = ib[y1c * 64 + x1c];
    out[i] = (1.f - ty) * ((1.f - tx) * v00 + tx * v01) + ty * ((1.f - tx) * v10 + tx * v11);
}

extern "C" void kernel_launch(void* const* d_in, const int* in_sizes, int n_in,
                              void* d_out, int out_size, void* d_ws, size_t ws_size,
                              hipStream_t stream)
{
    const float* t1       = (const float*)d_in[0];
    const float* t2       = (const float*)d_in[1];
    const float* t1_w     = (const float*)d_in[2];
    const float* t1_b     = (const float*)d_in[3];
    const float* t2_w     = (const float*)d_in[4];
    const float* t2_b     = (const float*)d_in[5];
    const float* df_res_w = (const float*)d_in[6];
    const float* df_res_b = (const float*)d_in[7];
    const float* df_res_s = (const float*)d_in[8];
    const float* df_res_o = (const float*)d_in[9];
    const float* df_b0_w  = (const float*)d_in[10];
    const float* df_b0_b  = (const float*)d_in[11];
    const float* df_b0_s  = (const float*)d_in[12];
    const float* df_b0_o  = (const float*)d_in[13];
    const float* df_b1_w  = (const float*)d_in[14];
    const float* df_b1_b  = (const float*)d_in[15];
    const float* df_b1_s  = (const float*)d_in[16];
    const float* df_b1_o  = (const float*)d_in[17];
    const float* df_fu_w  = (const float*)d_in[18];
    const float* df_fu_b  = (const float*)d_in[19];
    const float* df_fu_s  = (const float*)d_in[20];
    const float* df_fu_o  = (const float*)d_in[21];
    const float* br1_w    = (const float*)d_in[22];
    const float* br1_b    = (const float*)d_in[23];
    const float* br2_w    = (const float*)d_in[24];
    const float* br2_b    = (const float*)d_in[25];
    const float* fu_w     = (const float*)d_in[26];
    const float* fu_b     = (const float*)d_in[27];
    const float* fu_s     = (const float*)d_in[28];
    const float* fu_o     = (const float*)d_in[29];

    float* ws = (float*)d_ws;
    float* res1 = ws;                   // 2,097,152 f  (res1 -> r -> inc1 fp32)
    float* res2 = ws + 2097152;         // 2,097,152 f  (res2 -> b01 -> inc2 fp32)
    float* xbuf = ws + 4194304;         // 4,194,304 f  (t1pk/t2pk early; dif; fused at +2M)
    float* scr  = ws + 8388608;         // 4,194,304 f  bf16/f32 scratch region
    float* abuf = ws + 12582912;        // 4,194,304 f  (xpk/b01pk early; concat(a1,a2) late)
    float* attnS_f = ws + 16777216;     // 524,288 f -> wp_t1/t2/res/fu1 early; attnS bf16 (packed)
    float* simv = ws + 17301504;        // 16,384 f (sim early; wp_fu2 late)
    float* mxb  = ws + 17317888;        // 8,192 f

    unsigned short* us     = (unsigned short*)scr;
    unsigned short* wp_b0  = us;                 // 73,728
    unsigned short* wp_b1  = us + 73728;         // 204,800
    unsigned short* wp_br1 = us + 278528;        // 147,456
    unsigned short* wp_br2 = us + 425984;        // 409,600 -> ends 835,584
    unsigned short* xt_r   = us + 851968;        // 2,367,488 -> ends 3,219,456
    unsigned short* xt_dif = us + 3219456;       // 2,367,488 -> ends 5,586,944
    unsigned short* incT1  = us + 5586944;       // 2,097,152 -> ends 7,684,096
    unsigned short* incT2  = us + 851968;        // 2,097,152 (overlays dead xt_r)
    unsigned short* attn_bf= us + 7684096;       // 524,288 -> ends 8,208,384 (f 4,104,192)
    float* scrF = scr;
    float* pmaxb = scrF + 4104192;      // 32,768 f
    float* psumb = scrF + 4136960;      // 32,768 f
    unsigned short* attnS  = (unsigned short*)attnS_f;
    // early-phase overlays (dead before their regions' later use)
    unsigned short* wp_t1  = (unsigned short*)attnS_f;       // 32,768 sh (dead before attnS)
    unsigned short* wp_t2  = wp_t1 + 32768;                  // 32,768 sh
    unsigned short* wp_res = wp_t1 + 65536;                  // 32,768 sh (dead before attnS)
    unsigned short* wp_fu1 = wp_t1 + 98304;                  // 16,384 sh (dead before attnS)
    unsigned short* wp_fu2 = (unsigned short*)simv;          // 32,768 sh (written after simv dead)
    unsigned short* t1pk   = (unsigned short*)xbuf;          // 4,194,304 sh (dead before dif)
    unsigned short* t2pk   = t1pk + 4194304;                 // 4,194,304 sh -> ends at scr
    unsigned short* xpk    = (unsigned short*)abuf;          // 4,194,304 sh (dead before abuf write)
    unsigned short* b01pk  = (unsigned short*)abuf;          // 2,097,152 sh (reuse; xpk dead first)
    unsigned short* abufpk = us;                             // 4,194,304 sh (scr all dead post-attn)

    dim3 blk(256);

    // fused: zero padded bf16 conv inputs + prepack all conv + t1/t2 weights + pack t1/t2
    setup_kernel<<<38600, blk, 0, stream>>>((uint4*)xt_r, 591872,
                                            df_b0_w, wp_b0, df_b1_w, wp_b1,
                                            br1_w, wp_br1, br2_w, wp_br2,
                                            t1_w, wp_t1, t2_w, wp_t2,
                                            t1, t1pk, t2, t2pk);

    // res1/res2 = 1x1 conv(t1/t2) via MFMA GEMM
    gemm1x1<8><<<dim3(256, 4), blk, 0, stream>>>(t1pk, wp_t1, t1_b, res1, 0, nullptr, nullptr, nullptr, nullptr);
    gemm1x1<8><<<dim3(256, 4), blk, 0, stream>>>(t2pk, wp_t2, t2_b, res2, 0, nullptr, nullptr, nullptr, nullptr);
    sim_kernel<<<4096, blk, 0, stream>>>(res1, res2, simv);
    x_kernel2<<<dim3(128, 4), blk, 0, stream>>>(res1, res2, simv, xpk);   // writes packed x directly
    simp_kernel3<<<dim3(32, 4, 4), blk, 0, stream>>>(res1, res2, simv, attn_bf);
    // late weight prepack (simv now dead; attnS region still free)
    prepack3<<<320, blk, 0, stream>>>(df_res_w, wp_res, df_fu_w, wp_fu1, fu_w, wp_fu2);
    // r = stdconv1x1(x) via MFMA GEMM (+ bf16 padded chunked copy)
    gemm1x1<8><<<dim3(256, 4), blk, 0, stream>>>(xpk, wp_res, df_res_b, res1, 1, df_res_s, df_res_o, nullptr, xt_r);
    // b0 3x3 -> res2[0:64], b1 5x5 -> res2[64:128]
    convk_mfma<3, 64, 1, 4><<<dim3(256, 4), blk, 0, stream>>>(xt_r, wp_b0, df_b0_b, res2, 128, 0, 1, df_b0_s, df_b0_o, nullptr);
    convk_mfma<5, 64, 1, 4><<<dim3(256, 4), blk, 0, stream>>>(xt_r, wp_b1, df_b1_b, res2, 128, 64, 1, df_b1_s, df_b1_o, nullptr);
    // dif = stdconv1x1(b01) + r via MFMA GEMM (+ bf16 padded chunked copy)
    packX<4><<<8192, blk, 0, stream>>>(res2, b01pk);
    gemm1x1<4><<<dim3(256, 4), blk, 0, stream>>>(b01pk, wp_fu1, df_fu_b, xbuf, 1, df_fu_s, df_fu_o, res1, xt_dif);
    // inc1/inc2 (fp32 + bf16 B-frag-packed incT)
    convk_mfma<3, 128, 2, 4><<<dim3(256, 4), blk, 0, stream>>>(xt_dif, wp_br1, br1_b, res1, 128, 0, 0, nullptr, nullptr, incT1);
    convk_mfma<5, 128, 2, 4><<<dim3(256, 4), blk, 0, stream>>>(xt_dif, wp_br2, br2_b, res2, 128, 0, 0, nullptr, nullptr, incT2);
    // attention
    attnA_pass1<<<dim3(32, 8, 4), blk, 0, stream>>>(attn_bf, incT1, incT2, pmaxb, psumb);
    attnA_scale2<<<4096, blk, 0, stream>>>(attn_bf, pmaxb, psumb, mxb, attnS);
    attn_passB4<<<dim3(128, 8), blk, 0, stream>>>(attn_bf, attnS, incT1, incT2, mxb, res1, res2, abuf);
    // fused = stdconv1x1(concat(a1,a2)) + dif via MFMA GEMM
    float* dif = xbuf;
    float* fused = xbuf + 2097152;
    packX<8><<<16384, blk, 0, stream>>>(abuf, abufpk);
    gemm1x1<8><<<dim3(256, 4), blk, 0, stream>>>(abufpk, wp_fu2, fu_b, fused, 1, fu_s, fu_o, dif, nullptr);
    // bilinear 2x upsample -> d_out
    upsample_kernel<<<32768, blk, 0, stream>>>(fused, (float*)d_out);
}